// Round 2
// baseline (2945.281 us; speedup 1.0000x reference)
//
#include <hip/hip_runtime.h>
#include <hip/hip_bf16.h>

// Sizes (fixed by the problem)
#define BSZ  4096
#define TS   31
#define DIN  124
#define HH   256
#define FEA  64
#define VV   20
#define NCC  100
#define RPB  32          // batch rows per block
#define NBLK (BSZ/RPB)   // 128 blocks

typedef __attribute__((ext_vector_type(8))) short bf16x8;   // 8 bf16 = 4 VGPR
typedef __attribute__((ext_vector_type(4))) float f32x4;

// workspace byte offsets (packed bf16 MFMA B-fragments)
// L0: 64 tiles x 12 kk  (K = [h0(256) | x(124) | bias1 | 0 0 0])
// L1: 64 tiles x 16 kk  (K = [h0(256) | h1(256)], B = [Wih1 | Whh1])
// HD:  8 tiles x  8 kk  (K = h1(256), rows = [Wout(20) | Wcv(100) | 0(8)])
#define OFF_L0   0u
#define OFF_L1   786432u
#define OFF_HD   1835008u
#define OFF_BG1  1900544u     // 1024 f32 (bih1+bhh1)
#define OFF_BHD  1904640u     // 128 f32  ([bout | bcv | 0])

__device__ __forceinline__ unsigned short f2bf(float f) {
    unsigned int u = __float_as_uint(f);
    unsigned int r = (u + 0x7FFFu + ((u >> 16) & 1u)) >> 16;
    return (unsigned short)r;
}
__device__ __forceinline__ float sigmoidf_(float x) {
    return 1.f / (1.f + __expf(-x));
}
__device__ __forceinline__ float tanhf_(float x) {
    float ax = fabsf(x);
    float e = __expf(-2.f * ax);
    float t = (1.f - e) / (1.f + e);
    return copysignf(t, x);
}

// ---------------------------------------------------------------------------
// Prep: pack weights into MFMA B-fragment blocks. Fragment fb is 64 lanes x
// 16B contiguous; lane l holds W[16*tile + (l&15)][k0 + j], k0 = kk*32 +
// (l>>4)*8, j = 0..7.
// ---------------------------------------------------------------------------
__global__ __launch_bounds__(256) void prep_kernel(
    const float* __restrict__ Wih0, const float* __restrict__ Whh0,
    const float* __restrict__ bih0, const float* __restrict__ bhh0,
    const float* __restrict__ Wih1, const float* __restrict__ Whh1,
    const float* __restrict__ bih1, const float* __restrict__ bhh1,
    const float* __restrict__ Wout, const float* __restrict__ bout,
    const float* __restrict__ Wcv,  const float* __restrict__ bcv,
    char* __restrict__ ws)
{
    const int NFRAG = 64*12 + 64*16 + 8*8;      // 1856 fragment blocks
    int u = blockIdx.x * 256 + threadIdx.x;
    if (u < NFRAG * 64) {
        int fb = u >> 6;
        int l  = u & 63;
        int r15 = l & 15, l4 = l >> 4;
        unsigned short tmp[8];
        int4* dst;
        if (fb < 768) {                          // layer 0
            int tile = fb / 12, kk = fb - tile * 12;
            int row = tile * 16 + r15;
            int k0  = kk * 32 + l4 * 8;
            #pragma unroll
            for (int j = 0; j < 8; j++) {
                int k = k0 + j;
                float v;
                if (k < 256) v = Whh0[row * HH + k];
                else {
                    int kp = k - 256;
                    v = (kp < DIN) ? Wih0[row * DIN + kp]
                      : (kp == DIN ? bih0[row] + bhh0[row] : 0.f);
                }
                tmp[j] = f2bf(v);
            }
            dst = (int4*)(ws + OFF_L0) + fb * 64 + l;
        } else if (fb < 1792) {                  // layer 1
            int f = fb - 768;
            int tile = f >> 4, kk = f & 15;
            int row = tile * 16 + r15;
            int k0  = kk * 32 + l4 * 8;
            #pragma unroll
            for (int j = 0; j < 8; j++) {
                int k = k0 + j;
                float v = (k < 256) ? Wih1[row * HH + k] : Whh1[row * HH + k - 256];
                tmp[j] = f2bf(v);
            }
            dst = (int4*)(ws + OFF_L1) + f * 64 + l;
        } else {                                 // head
            int f = fb - 1792;
            int tile = f >> 3, kk = f & 7;
            int row = tile * 16 + r15;
            int k0  = kk * 32 + l4 * 8;
            #pragma unroll
            for (int j = 0; j < 8; j++) {
                int k = k0 + j;
                float v = (row < VV) ? Wout[row * HH + k]
                        : (row < VV + NCC ? Wcv[(row - VV) * HH + k] : 0.f);
                tmp[j] = f2bf(v);
            }
            dst = (int4*)(ws + OFF_HD) + f * 64 + l;
        }
        *dst = *(const int4*)tmp;
    } else if (u < NFRAG * 64 + 1024) {
        int g = u - NFRAG * 64;
        ((float*)(ws + OFF_BG1))[g] = bih1[g] + bhh1[g];
    } else if (u < NFRAG * 64 + 1024 + 128) {
        int v = u - NFRAG * 64 - 1024;
        float b = (v < VV) ? bout[v] : (v < VV + NCC ? bcv[v - VV] : 0.f);
        ((float*)(ws + OFF_BHD))[v] = b;
    }
}

// ---------------------------------------------------------------------------
// Main: 128 blocks x 1024 threads (16 waves). Block owns 32 batch rows.
// Wave w owns hidden cols [16w,16w+16): gate tiles {w,16+w,32+w,48+w}.
// A operand rows = batch rows (two 16-row groups); weights streamed from ws.
// ---------------------------------------------------------------------------
__global__ __launch_bounds__(1024, 4) void lstm_main(
    const float* __restrict__ x,        // [4096,64]
    const int*   __restrict__ choices,  // [4096,31]
    const int*   __restrict__ masks,    // [4096,31,20]
    const int*   __restrict__ c_idx,    // [4096,31]
    const int*   __restrict__ c_choice, // [4096,31]
    const float* __restrict__ Wxc,      // [256,64]
    const float* __restrict__ bxc,      // [256]
    const char*  __restrict__ ws,
    float* __restrict__ out)            // [4096]
{
    const int tid  = threadIdx.x;
    const int w    = tid >> 6;          // wave 0..15
    const int lane = tid & 63;
    const int l15  = lane & 15;
    const int l4   = lane >> 4;         // 0..3
    const int b0   = blockIdx.x * RPB;

    __shared__ unsigned short hsA[RPB][520];  // cols 0-255 h0, 256-511 h1 (pad 8)
    __shared__ unsigned short xs[RPB][128];   // x bits (0..123), 124 = 1.0, 125-127 = 0
    __shared__ float headbuf[RPB][132];
    __shared__ float xrow[RPB][64];
    __shared__ float lp_s[RPB];
    __shared__ int   ch_s[RPB];

    const bf16x8* pL0 = (const bf16x8*)(ws + OFF_L0);
    const bf16x8* pL1 = (const bf16x8*)(ws + OFF_L1);
    const bf16x8* pHD = (const bf16x8*)(ws + OFF_HD);
    const float* bg1   = (const float*)(ws + OFF_BG1);
    const float* bhead = (const float*)(ws + OFF_BHD);

    for (int i = tid; i < RPB * 520; i += 1024) ((unsigned short*)hsA)[i] = 0;
    for (int i = tid; i < RPB * 128; i += 1024) ((unsigned short*)xs)[i] = 0;
    for (int i = tid; i < RPB * 64; i += 1024)
        xrow[i >> 6][i & 63] = x[(b0 + (i >> 6)) * FEA + (i & 63)];
    if (tid < RPB) { lp_s[tid] = 0.f; }
    __syncthreads();
    if (tid < RPB) xs[tid][124] = 0x3F80;     // 1.0 bf16 (bias slot)
    __syncthreads();

    // c0 = x @ Wxc.T + bxc  (both layers start from it)
    const int hid = 16 * w + l15;
    float c0r[2][4], c1r[2][4];
    {
        float acc[2][4] = {{0.f,0.f,0.f,0.f},{0.f,0.f,0.f,0.f}};
        const float4* wxc4 = (const float4*)(Wxc + hid * FEA);
        #pragma unroll
        for (int k4 = 0; k4 < 16; k4++) {
            float4 wv = wxc4[k4];
            #pragma unroll
            for (int rg = 0; rg < 2; rg++)
                #pragma unroll
                for (int r = 0; r < 4; r++) {
                    const float4 xv = *(const float4*)&xrow[rg*16 + l4*4 + r][k4*4];
                    acc[rg][r] += wv.x*xv.x + wv.y*xv.y + wv.z*xv.z + wv.w*xv.w;
                }
        }
        float bb = bxc[hid];
        #pragma unroll
        for (int rg = 0; rg < 2; rg++)
            #pragma unroll
            for (int r = 0; r < 4; r++) { c0r[rg][r] = acc[rg][r] + bb; c1r[rg][r] = acc[rg][r] + bb; }
    }

    // hoisted per-wave constants
    const bf16x8* pb0L0 = pL0 + (size_t)((0*16 + w) * 12) * 64 + lane;
    const bf16x8* pb1L0 = pL0 + (size_t)((1*16 + w) * 12) * 64 + lane;
    const bf16x8* pb2L0 = pL0 + (size_t)((2*16 + w) * 12) * 64 + lane;
    const bf16x8* pb3L0 = pL0 + (size_t)((3*16 + w) * 12) * 64 + lane;
    const bf16x8* pb0L1 = pL1 + (size_t)((0*16 + w) * 16) * 64 + lane;
    const bf16x8* pb1L1 = pL1 + (size_t)((1*16 + w) * 16) * 64 + lane;
    const bf16x8* pb2L1 = pL1 + (size_t)((2*16 + w) * 16) * 64 + lane;
    const bf16x8* pb3L1 = pL1 + (size_t)((3*16 + w) * 16) * 64 + lane;
    const float bb1_0 = bg1[(0*16 + w) * 16 + l15];
    const float bb1_1 = bg1[(1*16 + w) * 16 + l15];
    const float bb1_2 = bg1[(2*16 + w) * 16 + l15];
    const float bb1_3 = bg1[(3*16 + w) * 16 + l15];
    const int th = w & 7, rgh = w >> 3;
    const bf16x8* pbHD = pHD + (size_t)(th * 8) * 64 + lane;
    const float bbHD = bhead[th * 16 + l15];

    for (int t = 0; t < TS; t++) {
        if (tid < RPB) ch_s[tid] = choices[(b0 + tid) * TS + t];

        // ---------------- layer 0: [h0 | x | 1] (K=384) ----------------
        f32x4 acc0[4][2];
        {
            f32x4 z; z[0]=0.f; z[1]=0.f; z[2]=0.f; z[3]=0.f;
            #pragma unroll
            for (int g = 0; g < 4; g++) { acc0[g][0] = z; acc0[g][1] = z; }
            #pragma unroll
            for (int kk = 0; kk < 12; kk++) {
                bf16x8 bf0 = pb0L0[kk * 64];
                bf16x8 bf1 = pb1L0[kk * 64];
                bf16x8 bf2 = pb2L0[kk * 64];
                bf16x8 bf3 = pb3L0[kk * 64];
                bf16x8 a0, a1;
                if (kk < 8) {
                    a0 = *(const bf16x8*)&hsA[l15][kk*32 + l4*8];
                    a1 = *(const bf16x8*)&hsA[16 + l15][kk*32 + l4*8];
                } else {
                    a0 = *(const bf16x8*)&xs[l15][(kk-8)*32 + l4*8];
                    a1 = *(const bf16x8*)&xs[16 + l15][(kk-8)*32 + l4*8];
                }
                acc0[0][0] = __builtin_amdgcn_mfma_f32_16x16x32_bf16(a0, bf0, acc0[0][0], 0, 0, 0);
                acc0[0][1] = __builtin_amdgcn_mfma_f32_16x16x32_bf16(a1, bf0, acc0[0][1], 0, 0, 0);
                acc0[1][0] = __builtin_amdgcn_mfma_f32_16x16x32_bf16(a0, bf1, acc0[1][0], 0, 0, 0);
                acc0[1][1] = __builtin_amdgcn_mfma_f32_16x16x32_bf16(a1, bf1, acc0[1][1], 0, 0, 0);
                acc0[2][0] = __builtin_amdgcn_mfma_f32_16x16x32_bf16(a0, bf2, acc0[2][0], 0, 0, 0);
                acc0[2][1] = __builtin_amdgcn_mfma_f32_16x16x32_bf16(a1, bf2, acc0[2][1], 0, 0, 0);
                acc0[3][0] = __builtin_amdgcn_mfma_f32_16x16x32_bf16(a0, bf3, acc0[3][0], 0, 0, 0);
                acc0[3][1] = __builtin_amdgcn_mfma_f32_16x16x32_bf16(a1, bf3, acc0[3][1], 0, 0, 0);
            }
        }
        __syncthreads();                 // hsA/xs reads done before h0 overwrite
        #pragma unroll
        for (int rg = 0; rg < 2; rg++)
            #pragma unroll
            for (int r = 0; r < 4; r++) {
                float iv = sigmoidf_(acc0[0][rg][r]);
                float fv = sigmoidf_(acc0[1][rg][r]);
                float gv = tanhf_(acc0[2][rg][r]);
                float ov = sigmoidf_(acc0[3][rg][r]);
                float cn = fv * c0r[rg][r] + iv * gv;
                c0r[rg][r] = cn;
                hsA[rg*16 + l4*4 + r][hid] = f2bf(ov * tanhf_(cn));
            }
        __syncthreads();                 // new h0 visible

        // ---------------- layer 1: [h0 | h1] (K=512) ----------------
        f32x4 acc1[4][2];
        {
            f32x4 c0v; c0v[0]=bb1_0; c0v[1]=bb1_0; c0v[2]=bb1_0; c0v[3]=bb1_0;
            f32x4 c1v; c1v[0]=bb1_1; c1v[1]=bb1_1; c1v[2]=bb1_1; c1v[3]=bb1_1;
            f32x4 c2v; c2v[0]=bb1_2; c2v[1]=bb1_2; c2v[2]=bb1_2; c2v[3]=bb1_2;
            f32x4 c3v; c3v[0]=bb1_3; c3v[1]=bb1_3; c3v[2]=bb1_3; c3v[3]=bb1_3;
            acc1[0][0] = c0v; acc1[0][1] = c0v;
            acc1[1][0] = c1v; acc1[1][1] = c1v;
            acc1[2][0] = c2v; acc1[2][1] = c2v;
            acc1[3][0] = c3v; acc1[3][1] = c3v;
            #pragma unroll
            for (int kk = 0; kk < 16; kk++) {
                bf16x8 bf0 = pb0L1[kk * 64];
                bf16x8 bf1 = pb1L1[kk * 64];
                bf16x8 bf2 = pb2L1[kk * 64];
                bf16x8 bf3 = pb3L1[kk * 64];
                bf16x8 a0 = *(const bf16x8*)&hsA[l15][kk*32 + l4*8];
                bf16x8 a1 = *(const bf16x8*)&hsA[16 + l15][kk*32 + l4*8];
                acc1[0][0] = __builtin_amdgcn_mfma_f32_16x16x32_bf16(a0, bf0, acc1[0][0], 0, 0, 0);
                acc1[0][1] = __builtin_amdgcn_mfma_f32_16x16x32_bf16(a1, bf0, acc1[0][1], 0, 0, 0);
                acc1[1][0] = __builtin_amdgcn_mfma_f32_16x16x32_bf16(a0, bf1, acc1[1][0], 0, 0, 0);
                acc1[1][1] = __builtin_amdgcn_mfma_f32_16x16x32_bf16(a1, bf1, acc1[1][1], 0, 0, 0);
                acc1[2][0] = __builtin_amdgcn_mfma_f32_16x16x32_bf16(a0, bf2, acc1[2][0], 0, 0, 0);
                acc1[2][1] = __builtin_amdgcn_mfma_f32_16x16x32_bf16(a1, bf2, acc1[2][1], 0, 0, 0);
                acc1[3][0] = __builtin_amdgcn_mfma_f32_16x16x32_bf16(a0, bf3, acc1[3][0], 0, 0, 0);
                acc1[3][1] = __builtin_amdgcn_mfma_f32_16x16x32_bf16(a1, bf3, acc1[3][1], 0, 0, 0);
            }
        }
        __syncthreads();                 // hsA reads done before h1 overwrite
        #pragma unroll
        for (int rg = 0; rg < 2; rg++)
            #pragma unroll
            for (int r = 0; r < 4; r++) {
                float iv = sigmoidf_(acc1[0][rg][r]);
                float fv = sigmoidf_(acc1[1][rg][r]);
                float gv = tanhf_(acc1[2][rg][r]);
                float ov = sigmoidf_(acc1[3][rg][r]);
                float cn = fv * c1r[rg][r] + iv * gv;
                c1r[rg][r] = cn;
                hsA[rg*16 + l4*4 + r][256 + hid] = f2bf(ov * tanhf_(cn));
            }
        __syncthreads();                 // new h1 visible

        // ---------------- head: [32,256] x [256,128] ----------------
        {
            f32x4 c; c[0]=bbHD; c[1]=bbHD; c[2]=bbHD; c[3]=bbHD;
            #pragma unroll
            for (int kk = 0; kk < 8; kk++) {
                bf16x8 bf_ = pbHD[kk * 64];
                bf16x8 a = *(const bf16x8*)&hsA[rgh*16 + l15][256 + kk*32 + l4*8];
                c = __builtin_amdgcn_mfma_f32_16x16x32_bf16(a, bf_, c, 0, 0, 0);
            }
            #pragma unroll
            for (int r = 0; r < 4; r++)
                headbuf[rgh*16 + l4*4 + r][th*16 + l15] = c[r];
        }
        __syncthreads();                 // headbuf + ch_s visible

        // ---------------- softmaxes + lp + x-bits (rows w, 16+w) ----------
        #pragma unroll
        for (int rr = 0; rr < 2; rr++) {
            const int row = rr * 16 + w;
            const int b = b0 + row;
            const int ch = ch_s[row];
            float v1;
            if (lane < VV) {
                int mk = masks[(b * TS + t) * VV + lane];
                v1 = mk ? headbuf[row][lane] : -1e9f;
            } else v1 = -__builtin_inff();
            float m = v1;
            #pragma unroll
            for (int off = 32; off; off >>= 1) m = fmaxf(m, __shfl_xor(m, off));
            float e = (lane < VV) ? __expf(v1 - m) : 0.f;
            #pragma unroll
            for (int off = 32; off; off >>= 1) e += __shfl_xor(e, off);
            float lse = m + __logf(e);
            float lv_ch = __shfl(v1, ch);
            float lpadd = lv_ch - lse;

            float a1v = headbuf[row][VV + lane];
            float a2v = (lane < 36) ? headbuf[row][VV + 64 + lane] : -__builtin_inff();
            float mc = fmaxf(a1v, a2v);
            #pragma unroll
            for (int off = 32; off; off >>= 1) mc = fmaxf(mc, __shfl_xor(mc, off));
            float ec = __expf(a1v - mc) + ((lane < 36) ? __expf(a2v - mc) : 0.f);
            #pragma unroll
            for (int off = 32; off; off >>= 1) ec += __shfl_xor(ec, off);
            float lsec = mc + __logf(ec);
            if (lane == 0) {
                int ci = c_idx[b * TS + t];
                float add2 = 0.f;
                if (ci) {
                    int cc = c_choice[b * TS + t];
                    add2 = headbuf[row][VV + cc] - lsec;
                }
                lp_s[row] += lpadd + add2;
            }
            if (lane < 4)
                xs[row][4*t + lane] = ((ch >> (3 - lane)) & 1) ? (unsigned short)0x3F80
                                                               : (unsigned short)0;
        }
        __syncthreads();                 // xs/lp/headbuf consistent for next step
    }

    if (tid < RPB) out[b0 + tid] = lp_s[tid];
}

extern "C" void kernel_launch(void* const* d_in, const int* in_sizes, int n_in,
                              void* d_out, int out_size, void* d_ws, size_t ws_size,
                              hipStream_t stream) {
    const float* x        = (const float*)d_in[0];
    const int*   choices  = (const int*)d_in[1];
    const int*   masks    = (const int*)d_in[2];
    const int*   c_idx    = (const int*)d_in[3];
    const int*   c_choice = (const int*)d_in[4];
    const float* Wih0 = (const float*)d_in[5];
    const float* Whh0 = (const float*)d_in[6];
    const float* bih0 = (const float*)d_in[7];
    const float* bhh0 = (const float*)d_in[8];
    const float* Wih1 = (const float*)d_in[9];
    const float* Whh1 = (const float*)d_in[10];
    const float* bih1 = (const float*)d_in[11];
    const float* bhh1 = (const float*)d_in[12];
    const float* Wout = (const float*)d_in[13];
    const float* bout = (const float*)d_in[14];
    const float* Wxc  = (const float*)d_in[15];
    const float* bxc  = (const float*)d_in[16];
    const float* Wcv  = (const float*)d_in[17];
    const float* bcv  = (const float*)d_in[18];
    char* ws = (char*)d_ws;

    hipLaunchKernelGGL(prep_kernel, dim3(469), dim3(256), 0, stream,
                       Wih0, Whh0, bih0, bhh0, Wih1, Whh1, bih1, bhh1,
                       Wout, bout, Wcv, bcv, ws);
    hipLaunchKernelGGL(lstm_main, dim3(NBLK), dim3(1024), 0, stream,
                       x, choices, masks, c_idx, c_choice,
                       Wxc, bxc, ws, (float*)d_out);
}

// Round 3
// 1932.609 us; speedup vs baseline: 1.5240x; 1.5240x over previous
//
#include <hip/hip_runtime.h>
#include <hip/hip_bf16.h>

// Problem sizes (fixed)
#define BSZ  4096
#define TS   31
#define DIN  124
#define HH   256
#define FEA  64
#define VV   20
#define NCC  100

#define NGROUP 16          // groups
#define NRANK  16          // blocks per group (weight slices)
#define GROWS  256         // batch rows per group

typedef __attribute__((ext_vector_type(8))) short bf16x8;   // 8 bf16 = 4 VGPR
typedef __attribute__((ext_vector_type(4))) float f32x4;

// ---- workspace layout (bytes) ----
#define OFF_WL0   0u          // 64 tiles x 12 kk x 1KB   = 786432
#define OFF_WL1   786432u     // 64 tiles x 16 kk x 1KB   = 1048576
#define OFF_WHD   1835008u    // 8 tiles x 8 kk x 1KB     = 65536
#define OFF_BG1   1900544u    // 1024 f32
#define OFF_BHD   1904640u    // 128 f32
#define OFF_SYNC  1905664u    // 16 groups x 64B counters
#define OFF_XREG  1907712u    // [4096][128] bf16 (bits | 1.0 at col 124)
#define OFF_HBUF  2956288u    // 2 x [4096][512] bf16 (h0 cols 0-255, h1 256-511)
#define OFF_HEADB 11344896u   // [4096][128] bf16 head logits
#define HSLOT     4194304u    // one hbuf slot = 4096*1024 B

__device__ __forceinline__ unsigned short f2bf(float f) {
    unsigned int u = __float_as_uint(f);
    unsigned int r = (u + 0x7FFFu + ((u >> 16) & 1u)) >> 16;
    return (unsigned short)r;
}
__device__ __forceinline__ float bf2f(unsigned short u) {
    return __uint_as_float(((unsigned)u) << 16);
}
__device__ __forceinline__ float sigmoidf_(float x) {
    return 1.f / (1.f + __expf(-x));
}
__device__ __forceinline__ float tanhf_(float x) {
    float ax = fabsf(x);
    float e = __expf(-2.f * ax);
    float t = (1.f - e) / (1.f + e);
    return copysignf(t, x);
}

// ---------------------------------------------------------------------------
// Prep: pack weights into MFMA B-fragment blocks (lane l of frag (tile,kk)
// holds W[16*tile + (l&15)][kk*32 + (l>>4)*8 + j], j=0..7). Fuse biases.
// Also set the xreg bias column (k=380 -> col 124) to 1.0.
// ---------------------------------------------------------------------------
__global__ __launch_bounds__(256) void prep_kernel(
    const float* __restrict__ Wih0, const float* __restrict__ Whh0,
    const float* __restrict__ bih0, const float* __restrict__ bhh0,
    const float* __restrict__ Wih1, const float* __restrict__ Whh1,
    const float* __restrict__ bih1, const float* __restrict__ bhh1,
    const float* __restrict__ Wout, const float* __restrict__ bout,
    const float* __restrict__ Wcv,  const float* __restrict__ bcv,
    char* __restrict__ ws)
{
    const int NFRAG = 64*12 + 64*16 + 8*8;      // 1856
    int u = blockIdx.x * 256 + threadIdx.x;
    if (u < NFRAG * 64) {
        int fb = u >> 6;
        int l  = u & 63;
        int r15 = l & 15, l4 = l >> 4;
        unsigned short tmp[8];
        int4* dst;
        if (fb < 768) {                          // layer 0: [Whh0 | Wih0 | bias]
            int tile = fb / 12, kk = fb - tile * 12;
            int row = tile * 16 + r15;
            int k0  = kk * 32 + l4 * 8;
            #pragma unroll
            for (int j = 0; j < 8; j++) {
                int k = k0 + j;
                float v;
                if (k < 256) v = Whh0[row * HH + k];
                else {
                    int kp = k - 256;
                    v = (kp < DIN) ? Wih0[row * DIN + kp]
                      : (kp == DIN ? bih0[row] + bhh0[row] : 0.f);
                }
                tmp[j] = f2bf(v);
            }
            dst = (int4*)(ws + OFF_WL0) + fb * 64 + l;
        } else if (fb < 1792) {                  // layer 1: [Wih1 | Whh1]
            int f = fb - 768;
            int tile = f >> 4, kk = f & 15;
            int row = tile * 16 + r15;
            int k0  = kk * 32 + l4 * 8;
            #pragma unroll
            for (int j = 0; j < 8; j++) {
                int k = k0 + j;
                float v = (k < 256) ? Wih1[row * HH + k] : Whh1[row * HH + k - 256];
                tmp[j] = f2bf(v);
            }
            dst = (int4*)(ws + OFF_WL1) + f * 64 + l;
        } else {                                 // head: [Wout | Wcv | 0]
            int f = fb - 1792;
            int tile = f >> 3, kk = f & 7;
            int row = tile * 16 + r15;
            int k0  = kk * 32 + l4 * 8;
            #pragma unroll
            for (int j = 0; j < 8; j++) {
                int k = k0 + j;
                float v = (row < VV) ? Wout[row * HH + k]
                        : (row < VV + NCC ? Wcv[(row - VV) * HH + k] : 0.f);
                tmp[j] = f2bf(v);
            }
            dst = (int4*)(ws + OFF_WHD) + f * 64 + l;
        }
        *dst = *(const int4*)tmp;
    } else if (u < NFRAG * 64 + 1024) {
        int g = u - NFRAG * 64;
        ((float*)(ws + OFF_BG1))[g] = bih1[g] + bhh1[g];
    } else if (u < NFRAG * 64 + 1024 + 128) {
        int v = u - NFRAG * 64 - 1024;
        float b = (v < VV) ? bout[v] : (v < VV + NCC ? bcv[v - VV] : 0.f);
        ((float*)(ws + OFF_BHD))[v] = b;
    } else if (u < NFRAG * 64 + 1024 + 128 + BSZ) {
        int row = u - (NFRAG * 64 + 1024 + 128);
        *(unsigned short*)(ws + OFF_XREG + (size_t)row * 256 + 248) = 0x3F80; // col 124 = 1.0
    }
}

// ---------------------------------------------------------------------------
// group sync: 16 blocks arrive on an agent-scope counter; 3 per step.
// ---------------------------------------------------------------------------
__device__ __forceinline__ void gsync(unsigned* cnt, unsigned target) {
    __syncthreads();                              // all waves done (drains stores)
    if (threadIdx.x == 0) {
        __threadfence();                          // release (L2 wb for cross-XCD)
        __hip_atomic_fetch_add(cnt, 1u, __ATOMIC_RELEASE, __HIP_MEMORY_SCOPE_AGENT);
        while (__hip_atomic_load(cnt, __ATOMIC_RELAXED, __HIP_MEMORY_SCOPE_AGENT) < target)
            __builtin_amdgcn_s_sleep(1);
        __threadfence();                          // acquire (invalidate stale)
    }
    __syncthreads();
}

// ---------------------------------------------------------------------------
// Main: grid = 256 blocks (1/CU). group g = bid&15 (same XCD under %8 rr),
// rank = bid>>4 owns hidden slice [16*rank,16*rank+16) with weights in LDS.
// Wave w handles the group's batch rows [16w,16w+16).
// ---------------------------------------------------------------------------
__global__ __launch_bounds__(1024, 4) void lstm_main(
    const float* __restrict__ x,        // [4096,64]
    const int*   __restrict__ choices,  // [4096,31]
    const int*   __restrict__ masks,    // [4096,31,20]
    const int*   __restrict__ c_idx,    // [4096,31]
    const int*   __restrict__ c_choice, // [4096,31]
    const float* __restrict__ Wxc,      // [256,64]
    const float* __restrict__ bxc,      // [256]
    char* __restrict__ ws,
    float* __restrict__ out)            // [4096]
{
    const int tid  = threadIdx.x;
    const int w    = tid >> 6;          // wave 0..15
    const int lane = tid & 63;
    const int l15  = lane & 15;
    const int l4   = lane >> 4;         // 0..3
    const int g    = blockIdx.x & 15;   // group
    const int rank = blockIdx.x >> 4;   // weight slice

    __shared__ int4 ldsL0[4][12][64];   // 48KB: gate-tile gt = global tile gt*16+rank
    __shared__ int4 ldsL1[4][16][64];   // 64KB
    __shared__ int4 ldsHD[8][64];       // 8KB: head tile rank&7

    // ---- load weight slices into LDS (once) ----
    {
        const int4* src = (const int4*)(ws + OFF_WL0);
        for (int i = tid; i < 4 * 12 * 64; i += 1024) {
            int gt = i / 768, r = i - gt * 768;          // r = kk*64 + l
            ((int4*)ldsL0)[i] = src[((gt * 16 + rank) * 12) * 64 + r];
        }
        src = (const int4*)(ws + OFF_WL1);
        for (int i = tid; i < 4 * 16 * 64; i += 1024) {
            int gt = i / 1024, r = i - gt * 1024;
            ((int4*)ldsL1)[i] = src[((gt * 16 + rank) * 16) * 64 + r];
        }
        src = (const int4*)(ws + OFF_WHD);
        for (int i = tid; i < 8 * 64; i += 1024)
            ((int4*)ldsHD)[i] = src[((rank & 7) * 8) * 64 + i];
    }

    // ---- c0 = x @ Wxc.T + bxc for (rows 16w.., units 16*rank + l15) ----
    float c0r[4], c1r[4];
    {
        const int unit = 16 * rank + l15;
        float acc[4] = {0.f, 0.f, 0.f, 0.f};
        const int rbase = (g * GROWS + 16 * w + l4 * 4) * FEA;
        #pragma unroll 4
        for (int k = 0; k < FEA; k++) {
            float wv = Wxc[unit * FEA + k];
            #pragma unroll
            for (int q = 0; q < 4; q++)
                acc[q] += wv * x[rbase + q * FEA + k];
        }
        float bb = bxc[unit];
        #pragma unroll
        for (int q = 0; q < 4; q++) { c0r[q] = acc[q] + bb; c1r[q] = acc[q] + bb; }
    }

    // hoisted biases
    float bb1[4], bbHD;
    {
        const float* bg1 = (const float*)(ws + OFF_BG1);
        #pragma unroll
        for (int gt = 0; gt < 4; gt++) bb1[gt] = bg1[(gt * 16 + rank) * 16 + l15];
        bbHD = ((const float*)(ws + OFF_BHD))[(rank & 7) * 16 + l15];
    }

    unsigned* cnt = (unsigned*)(ws + OFF_SYNC) + g * 16;
    unsigned tgt = NRANK;
    const int sr = g * GROWS + 16 * rank + w;    // this wave's softmax row
    float lp = 0.f;
    const int arow = g * GROWS + 16 * w + l15;   // A-operand row for this lane
    const int crow = g * GROWS + 16 * w + l4*4;  // C rows base (+q)

    __syncthreads();

    for (int t = 0; t < TS; t++) {
        const int p = t & 1, pp = p ^ 1;
        const char* hb_prev = ws + OFF_HBUF + pp * HSLOT;
        char*       hb_cur  = ws + OFF_HBUF + p  * HSLOT;

        // ================= phase A: layer 0, K = [h0 | x | 1] =================
        {
            bf16x8 a[12];
            const char* ar = hb_prev + (size_t)arow * 1024 + l4 * 16;
            #pragma unroll
            for (int kk = 0; kk < 8; kk++) a[kk] = *(const bf16x8*)(ar + kk * 64);
            const char* xr = ws + OFF_XREG + (size_t)arow * 256 + l4 * 16;
            #pragma unroll
            for (int kk = 0; kk < 4; kk++) a[8 + kk] = *(const bf16x8*)(xr + kk * 64);

            f32x4 acc[4];
            #pragma unroll
            for (int gt = 0; gt < 4; gt++) { f32x4 z; z[0]=z[1]=z[2]=z[3]=0.f; acc[gt]=z; }
            #pragma unroll
            for (int kk = 0; kk < 12; kk++) {
                #pragma unroll
                for (int gt = 0; gt < 4; gt++) {
                    bf16x8 bfr = *(const bf16x8*)&ldsL0[gt][kk][lane];
                    acc[gt] = __builtin_amdgcn_mfma_f32_16x16x32_bf16(a[kk], bfr, acc[gt], 0, 0, 0);
                }
            }
            #pragma unroll
            for (int q = 0; q < 4; q++) {
                float iv = sigmoidf_(acc[0][q]);
                float fv = sigmoidf_(acc[1][q]);
                float gv = tanhf_(acc[2][q]);
                float ov = sigmoidf_(acc[3][q]);
                float cn = fv * c0r[q] + iv * gv;
                c0r[q] = cn;
                *(unsigned short*)(hb_cur + (size_t)(crow + q) * 1024 + (16 * rank + l15) * 2)
                    = f2bf(ov * tanhf_(cn));
            }
        }
        gsync(cnt, tgt); tgt += NRANK;

        // ================= phase B: layer 1, K = [h0_new | h1_prev] ===========
        {
            bf16x8 a[16];
            const char* ar0 = hb_cur  + (size_t)arow * 1024 + l4 * 16;        // h0(t)
            const char* ar1 = hb_prev + (size_t)arow * 1024 + 512 + l4 * 16;  // h1(t-1)
            #pragma unroll
            for (int kk = 0; kk < 8; kk++) a[kk]     = *(const bf16x8*)(ar0 + kk * 64);
            #pragma unroll
            for (int kk = 0; kk < 8; kk++) a[8 + kk] = *(const bf16x8*)(ar1 + kk * 64);

            f32x4 acc[4];
            #pragma unroll
            for (int gt = 0; gt < 4; gt++) { f32x4 z; z[0]=z[1]=z[2]=z[3]=bb1[gt]; acc[gt]=z; }
            #pragma unroll
            for (int kk = 0; kk < 16; kk++) {
                #pragma unroll
                for (int gt = 0; gt < 4; gt++) {
                    bf16x8 bfr = *(const bf16x8*)&ldsL1[gt][kk][lane];
                    acc[gt] = __builtin_amdgcn_mfma_f32_16x16x32_bf16(a[kk], bfr, acc[gt], 0, 0, 0);
                }
            }
            #pragma unroll
            for (int q = 0; q < 4; q++) {
                float iv = sigmoidf_(acc[0][q]);
                float fv = sigmoidf_(acc[1][q]);
                float gv = tanhf_(acc[2][q]);
                float ov = sigmoidf_(acc[3][q]);
                float cn = fv * c1r[q] + iv * gv;
                c1r[q] = cn;
                *(unsigned short*)(hb_cur + (size_t)(crow + q) * 1024 + 512 + (16 * rank + l15) * 2)
                    = f2bf(ov * tanhf_(cn));
            }
        }
        gsync(cnt, tgt); tgt += NRANK;

        // ================= phase C: bits + head, then softmax =================
        int chv = 0;
        if (lane == 0) chv = choices[sr * TS + t];
        chv = __shfl(chv, 0);
        if (lane < 4)
            *(unsigned short*)(ws + OFF_XREG + (size_t)sr * 256 + (4 * t + lane) * 2)
                = ((chv >> (3 - lane)) & 1) ? (unsigned short)0x3F80 : (unsigned short)0;

        if (w < 8) {   // head MFMA: this block covers 128 rows x its 16 head cols
            const int mrow = g * GROWS + ((rank < 8) ? 0 : 128) + 16 * w;
            bf16x8 ah[8];
            const char* ar = hb_cur + (size_t)(mrow + l15) * 1024 + 512 + l4 * 16;
            #pragma unroll
            for (int kk = 0; kk < 8; kk++) ah[kk] = *(const bf16x8*)(ar + kk * 64);
            f32x4 hc; hc[0]=hc[1]=hc[2]=hc[3]=bbHD;
            #pragma unroll
            for (int kk = 0; kk < 8; kk++) {
                bf16x8 bfr = *(const bf16x8*)&ldsHD[kk][lane];
                hc = __builtin_amdgcn_mfma_f32_16x16x32_bf16(ah[kk], bfr, hc, 0, 0, 0);
            }
            #pragma unroll
            for (int q = 0; q < 4; q++)
                *(unsigned short*)(ws + OFF_HEADB + (size_t)(mrow + l4 * 4 + q) * 256
                                   + ((rank & 7) * 16 + l15) * 2) = f2bf(hc[q]);
        }
        gsync(cnt, tgt); tgt += NRANK;

        // softmaxes + lp for row sr (one wave per row)
        {
            const ushort2 hv2 = *(const ushort2*)(ws + OFF_HEADB + (size_t)sr * 256 + lane * 4);
            const float v0 = bf2f(hv2.x), v1 = bf2f(hv2.y);
            const float NINF = -__builtin_inff();

            float tv0 = NINF, tv1 = NINF;
            if (lane < 10) {
                int2 mk = *(const int2*)(masks + ((size_t)sr * TS + t) * VV + 2 * lane);
                tv0 = mk.x ? v0 : -1e9f;
                tv1 = mk.y ? v1 : -1e9f;
            }
            float m = fmaxf(tv0, tv1);
            #pragma unroll
            for (int off = 32; off; off >>= 1) m = fmaxf(m, __shfl_xor(m, off));
            float e = (lane < 10) ? (__expf(tv0 - m) + __expf(tv1 - m)) : 0.f;
            #pragma unroll
            for (int off = 32; off; off >>= 1) e += __shfl_xor(e, off);
            float lse = m + __logf(e);
            float chlog = __shfl((chv & 1) ? tv1 : tv0, chv >> 1);
            float lpadd = chlog - lse;

            const bool va = (lane >= 10) && (lane < 60);
            float cv0 = va ? v0 : NINF, cv1 = va ? v1 : NINF;
            float mc = fmaxf(cv0, cv1);
            #pragma unroll
            for (int off = 32; off; off >>= 1) mc = fmaxf(mc, __shfl_xor(mc, off));
            float ec = va ? (__expf(cv0 - mc) + __expf(cv1 - mc)) : 0.f;
            #pragma unroll
            for (int off = 32; off; off >>= 1) ec += __shfl_xor(ec, off);
            float lsec = mc + __logf(ec);

            int civ = 0, ccv = 0;
            if (lane == 0) { civ = c_idx[sr * TS + t]; ccv = c_choice[sr * TS + t]; }
            civ = __shfl(civ, 0); ccv = __shfl(ccv, 0);
            if (civ) {
                int col = VV + ccv;
                float cl = __shfl((col & 1) ? cv1 : cv0, col >> 1);
                lpadd += cl - lsec;
            }
            lp += lpadd;
        }
        // no trailing sync needed: next phase A's writes target the buffer slot
        // whose last readers all completed before sync1 of this step.
    }

    if (lane == 0) out[sr] = lp;
}

extern "C" void kernel_launch(void* const* d_in, const int* in_sizes, int n_in,
                              void* d_out, int out_size, void* d_ws, size_t ws_size,
                              hipStream_t stream) {
    const float* x        = (const float*)d_in[0];
    const int*   choices  = (const int*)d_in[1];
    const int*   masks    = (const int*)d_in[2];
    const int*   c_idx    = (const int*)d_in[3];
    const int*   c_choice = (const int*)d_in[4];
    const float* Wih0 = (const float*)d_in[5];
    const float* Whh0 = (const float*)d_in[6];
    const float* bih0 = (const float*)d_in[7];
    const float* bhh0 = (const float*)d_in[8];
    const float* Wih1 = (const float*)d_in[9];
    const float* Whh1 = (const float*)d_in[10];
    const float* bih1 = (const float*)d_in[11];
    const float* bhh1 = (const float*)d_in[12];
    const float* Wout = (const float*)d_in[13];
    const float* bout = (const float*)d_in[14];
    const float* Wxc  = (const float*)d_in[15];
    const float* bxc  = (const float*)d_in[16];
    const float* Wcv  = (const float*)d_in[17];
    const float* bcv  = (const float*)d_in[18];
    char* ws = (char*)d_ws;

    // zero sync counters, x-bit region, h buffers (re-poisoned to 0xAA each run)
    hipMemsetAsync(ws + OFF_SYNC, 0, 1024, stream);
    hipMemsetAsync(ws + OFF_XREG, 0, 1048576, stream);
    hipMemsetAsync(ws + OFF_HBUF, 0, 8388608, stream);

    hipLaunchKernelGGL(prep_kernel, dim3(485), dim3(256), 0, stream,
                       Wih0, Whh0, bih0, bhh0, Wih1, Whh1, bih1, bhh1,
                       Wout, bout, Wcv, bcv, ws);
    hipLaunchKernelGGL(lstm_main, dim3(256), dim3(1024), 0, stream,
                       x, choices, masks, c_idx, c_choice,
                       Wxc, bxc, ws, (float*)d_out);
}

// Round 4
// 1359.780 us; speedup vs baseline: 2.1660x; 1.4213x over previous
//
#include <hip/hip_runtime.h>
#include <hip/hip_bf16.h>

// Problem sizes (fixed)
#define BSZ  4096
#define TS   31
#define DIN  124
#define HH   256
#define FEA  64
#define VV   20
#define NCC  100

#define NGROUP 16          // groups
#define NRANK  16          // blocks per group (hidden slices)
#define GROWS  256         // batch rows per group

typedef __attribute__((ext_vector_type(8))) short bf16x8;   // 8 bf16 = 4 VGPR
typedef __attribute__((ext_vector_type(4))) float f32x4;

// ---- workspace layout (bytes) ----
#define OFF_WL0   0u          // 64 tiles x 12 kk x 1KB = 786432
#define OFF_WL1   786432u     // 64 tiles x 16 kk x 1KB = 1048576
#define OFF_WHD   1835008u    // 8 tiles x 8 kk x 1KB   = 65536
#define OFF_BG1   1900544u    // 1024 f32
#define OFF_BHD   1904640u    // 128 f32
#define OFF_SYNC  1905664u    // 16 groups x 64B counters
#define OFF_XREG  1907712u    // [4096][128] bf16 full bit pattern (+1.0 at col 124)
#define OFF_HBUF  2956288u    // 2 x [4096][512] bf16 (h0 cols 0-255, h1 256-511)
#define HSLOT     4194304u    // one hbuf slot

__device__ __forceinline__ unsigned short f2bf(float f) {
    unsigned int u = __float_as_uint(f);
    unsigned int r = (u + 0x7FFFu + ((u >> 16) & 1u)) >> 16;
    return (unsigned short)r;
}
__device__ __forceinline__ float sigmoidf_(float x) {
    return 1.f / (1.f + __expf(-x));
}
__device__ __forceinline__ float tanhf_(float x) {
    float ax = fabsf(x);
    float e = __expf(-2.f * ax);
    float t = (1.f - e) / (1.f + e);
    return copysignf(t, x);
}

// ---------------------------------------------------------------------------
// Prep: pack weights into MFMA B-fragment blocks (lane l of frag (tile,kk)
// holds W[16*tile + (l&15)][kk*32 + (l>>4)*8 + j], j=0..7). Fuse biases.
// ---------------------------------------------------------------------------
__global__ __launch_bounds__(256) void prep_kernel(
    const float* __restrict__ Wih0, const float* __restrict__ Whh0,
    const float* __restrict__ bih0, const float* __restrict__ bhh0,
    const float* __restrict__ Wih1, const float* __restrict__ Whh1,
    const float* __restrict__ bih1, const float* __restrict__ bhh1,
    const float* __restrict__ Wout, const float* __restrict__ bout,
    const float* __restrict__ Wcv,  const float* __restrict__ bcv,
    char* __restrict__ ws)
{
    const int NFRAG = 64*12 + 64*16 + 8*8;      // 1856
    int u = blockIdx.x * 256 + threadIdx.x;
    if (u < NFRAG * 64) {
        int fb = u >> 6;
        int l  = u & 63;
        int r15 = l & 15, l4 = l >> 4;
        unsigned short tmp[8];
        int4* dst;
        if (fb < 768) {                          // layer 0: [Whh0 | Wih0 | bias]
            int tile = fb / 12, kk = fb - tile * 12;
            int row = tile * 16 + r15;
            int k0  = kk * 32 + l4 * 8;
            #pragma unroll
            for (int j = 0; j < 8; j++) {
                int k = k0 + j;
                float v;
                if (k < 256) v = Whh0[row * HH + k];
                else {
                    int kp = k - 256;
                    v = (kp < DIN) ? Wih0[row * DIN + kp]
                      : (kp == DIN ? bih0[row] + bhh0[row] : 0.f);
                }
                tmp[j] = f2bf(v);
            }
            dst = (int4*)(ws + OFF_WL0) + fb * 64 + l;
        } else if (fb < 1792) {                  // layer 1: [Wih1 | Whh1]
            int f = fb - 768;
            int tile = f >> 4, kk = f & 15;
            int row = tile * 16 + r15;
            int k0  = kk * 32 + l4 * 8;
            #pragma unroll
            for (int j = 0; j < 8; j++) {
                int k = k0 + j;
                float v = (k < 256) ? Wih1[row * HH + k] : Whh1[row * HH + k - 256];
                tmp[j] = f2bf(v);
            }
            dst = (int4*)(ws + OFF_WL1) + f * 64 + l;
        } else {                                 // head: [Wout | Wcv | 0]
            int f = fb - 1792;
            int tile = f >> 3, kk = f & 7;
            int row = tile * 16 + r15;
            int k0  = kk * 32 + l4 * 8;
            #pragma unroll
            for (int j = 0; j < 8; j++) {
                int k = k0 + j;
                float v = (row < VV) ? Wout[row * HH + k]
                        : (row < VV + NCC ? Wcv[(row - VV) * HH + k] : 0.f);
                tmp[j] = f2bf(v);
            }
            dst = (int4*)(ws + OFF_WHD) + f * 64 + l;
        }
        *dst = *(const int4*)tmp;
    } else if (u < NFRAG * 64 + 1024) {
        int g = u - NFRAG * 64;
        ((float*)(ws + OFF_BG1))[g] = bih1[g] + bhh1[g];
    } else if (u < NFRAG * 64 + 1024 + 128) {
        int v = u - NFRAG * 64 - 1024;
        float b = (v < VV) ? bout[v] : (v < VV + NCC ? bcv[v - VV] : 0.f);
        ((float*)(ws + OFF_BHD))[v] = b;
    }
}

// ---------------------------------------------------------------------------
// group sync: 16 blocks arrive on an agent-scope counter; ONE per epoch.
// ---------------------------------------------------------------------------
__device__ __forceinline__ void gsync(unsigned* cnt, unsigned target) {
    __syncthreads();                              // all waves done (drains stores)
    if (threadIdx.x == 0) {
        __threadfence();                          // release
        __hip_atomic_fetch_add(cnt, 1u, __ATOMIC_RELEASE, __HIP_MEMORY_SCOPE_AGENT);
        while (__hip_atomic_load(cnt, __ATOMIC_RELAXED, __HIP_MEMORY_SCOPE_AGENT) < target)
            __builtin_amdgcn_s_sleep(2);
        __threadfence();                          // acquire
    }
    __syncthreads();
}

// ---------------------------------------------------------------------------
// Main: grid = 256 (1/CU). g = bid&15 (group, XCD-local), rank = bid>>4 owns
// hidden slice [16*rank,16*rank+16), weights in LDS. 512 threads (8 waves);
// wave w handles group rows [32w,32w+32) for L0/L1, head col-tile w, and
// softmax for own-block rows {2w, 2w+1}.
// Epoch e: L0(t=e), L1(t=e-1), head+softmax(t=e-2); one group sync per epoch.
// ---------------------------------------------------------------------------
__global__ __launch_bounds__(512, 2) void lstm_main(
    const float* __restrict__ x,        // [4096,64]
    const int*   __restrict__ choices,  // [4096,31]
    const int*   __restrict__ masks,    // [4096,31,20]
    const int*   __restrict__ c_idx,    // [4096,31]
    const int*   __restrict__ c_choice, // [4096,31]
    const float* __restrict__ Wxc,      // [256,64]
    const float* __restrict__ bxc,      // [256]
    char* __restrict__ ws,
    float* __restrict__ out)            // [4096]
{
    const int tid  = threadIdx.x;
    const int w    = tid >> 6;          // wave 0..7
    const int lane = tid & 63;
    const int l15  = lane & 15;
    const int l4   = lane >> 4;         // 0..3
    const int g    = blockIdx.x & 15;   // group (all ranks same XCD under %8 rr)
    const int rank = blockIdx.x >> 4;   // hidden slice

    __shared__ int4 ldsL0[4][12][64];   // 48KB
    __shared__ int4 ldsL1[4][16][64];   // 64KB
    __shared__ float headbuf[16][132];  // 8.25KB f32 logits for own 16 rows
    __shared__ int choices_lds[16][TS];
    __shared__ int cidx_lds[16][TS];
    __shared__ int cch_lds[16][TS];

    const int obase = g * GROWS + 16 * rank;      // own softmax rows base
    const int arow0 = g * GROWS + 32 * w + l15;   // A row (rg adds 16)
    const int crow0 = g * GROWS + 32 * w + l4*4;  // C row base (+16rg+q)

    // ---- load weight slices into LDS ----
    {
        const int4* src = (const int4*)(ws + OFF_WL0);
        for (int i = tid; i < 4 * 12 * 64; i += 512) {
            int gt = i / 768, r = i - gt * 768;
            ((int4*)ldsL0)[i] = src[((gt * 16 + rank) * 12) * 64 + r];
        }
        src = (const int4*)(ws + OFF_WL1);
        for (int i = tid; i < 4 * 16 * 64; i += 512) {
            int gt = i / 1024, r = i - gt * 1024;
            ((int4*)ldsL1)[i] = src[((gt * 16 + rank) * 16) * 64 + r];
        }
    }
    // head weight col-tile w in registers (persistent)
    bf16x8 whd[8];
    #pragma unroll
    for (int kk = 0; kk < 8; kk++)
        whd[kk] = *(const bf16x8*)(ws + OFF_WHD + ((size_t)(w * 8 + kk) * 64 + lane) * 16);

    // ---- write own rows' full x-bit pattern (masked per-epoch at read) ----
    for (int i = tid; i < 16 * 128; i += 512) {
        int r = i >> 7, col = i & 127;
        unsigned short v = 0;
        if (col < 124) {
            int ch = choices[(obase + r) * TS + (col >> 2)];
            v = ((ch >> (3 - (col & 3))) & 1) ? (unsigned short)0x3F80 : (unsigned short)0;
        } else if (col == 124) v = 0x3F80;
        *(unsigned short*)(ws + OFF_XREG + (size_t)(obase + r) * 256 + col * 2) = v;
    }
    // ---- preload per-row scalars into LDS ----
    for (int i = tid; i < 16 * TS; i += 512) {
        int r = i / TS, tt = i - r * TS;
        choices_lds[r][tt] = choices[(obase + r) * TS + tt];
        cidx_lds[r][tt]    = c_idx[(obase + r) * TS + tt];
        cch_lds[r][tt]     = c_choice[(obase + r) * TS + tt];
    }

    // ---- c0 = x @ Wxc.T + bxc ----
    float c0r[2][4], c1r[2][4];
    {
        const int unit = 16 * rank + l15;
        float acc[2][4] = {{0.f,0.f,0.f,0.f},{0.f,0.f,0.f,0.f}};
        #pragma unroll 4
        for (int k4 = 0; k4 < 16; k4++) {
            float4 wv = *(const float4*)(Wxc + unit * FEA + k4 * 4);
            #pragma unroll
            for (int rg = 0; rg < 2; rg++)
                #pragma unroll
                for (int q = 0; q < 4; q++) {
                    int row = g * GROWS + 32 * w + 16 * rg + l4 * 4 + q;
                    float4 xv = *(const float4*)(x + row * FEA + k4 * 4);
                    acc[rg][q] += wv.x*xv.x + wv.y*xv.y + wv.z*xv.z + wv.w*xv.w;
                }
        }
        float bb = bxc[unit];
        #pragma unroll
        for (int rg = 0; rg < 2; rg++)
            #pragma unroll
            for (int q = 0; q < 4; q++) { c0r[rg][q] = acc[rg][q] + bb; c1r[rg][q] = acc[rg][q] + bb; }
    }

    // hoisted biases
    float bb1[4], bbHD;
    {
        const float* bg1 = (const float*)(ws + OFF_BG1);
        #pragma unroll
        for (int gt = 0; gt < 4; gt++) bb1[gt] = bg1[(gt * 16 + rank) * 16 + l15];
        bbHD = ((const float*)(ws + OFF_BHD))[w * 16 + l15];
    }

    unsigned* cnt = (unsigned*)(ws + OFF_SYNC) + g * 16;
    unsigned tgt = NRANK;
    float lp = 0.f;
    const int half = lane >> 5, ln = lane & 31;
    const int srow = 2 * w + half;                // own softmax row (0..15)

    __syncthreads();

    for (int e = 0; e <= 32; e++) {
        const char* rs  = ws + OFF_HBUF + (size_t)((unsigned)(e + 1) & 1u) * HSLOT; // slot (e-1)&1
        char*       wsl = ws + OFF_HBUF + (size_t)((unsigned)e & 1u) * HSLOT;
        const bool doL0 = (e < TS);
        const bool doL1 = (e >= 1 && e <= TS);
        const bool doHD = (e >= 2);
        const int  tH   = e - 2;

        // ---- early loads: h0(e-1) frags (shared by L0 and L1), h1(e-2), x ----
        bf16x8 a0[2][8], a1[2][8], ax[2][4];
        if (doL0 || doL1) {
            #pragma unroll
            for (int rg = 0; rg < 2; rg++) {
                const char* ar = rs + (size_t)(arow0 + 16 * rg) * 1024 + l4 * 16;
                #pragma unroll
                for (int kk = 0; kk < 8; kk++) a0[rg][kk] = *(const bf16x8*)(ar + kk * 64);
            }
        }
        if (doL1) {
            #pragma unroll
            for (int rg = 0; rg < 2; rg++) {
                const char* ar = rs + (size_t)(arow0 + 16 * rg) * 1024 + 512 + l4 * 16;
                #pragma unroll
                for (int kk = 0; kk < 8; kk++) a1[rg][kk] = *(const bf16x8*)(ar + kk * 64);
            }
        }
        if (doL0) {
            if (e == 0) {
                #pragma unroll
                for (int rg = 0; rg < 2; rg++)
                    #pragma unroll
                    for (int kk = 0; kk < 4; kk++) {
                        bf16x8 z = {0,0,0,0,0,0,0,0};
                        if (kk == 3 && l4 == 3) z[4] = (short)0x3F80;  // bias col 124
                        ax[rg][kk] = z;
                    }
            } else {
                #pragma unroll
                for (int rg = 0; rg < 2; rg++) {
                    const char* xr = ws + OFF_XREG + (size_t)(arow0 + 16 * rg) * 256 + l4 * 16;
                    #pragma unroll
                    for (int kk = 0; kk < 4; kk++) ax[rg][kk] = *(const bf16x8*)(xr + kk * 64);
                }
                // mask out future bits: keep col < 4e or col >= 124
                #pragma unroll
                for (int rg = 0; rg < 2; rg++)
                    #pragma unroll
                    for (int kk = 0; kk < 4; kk++)
                        #pragma unroll
                        for (int j = 0; j < 8; j++) {
                            int col = kk * 32 + l4 * 8 + j;
                            if (!(col < 4 * e || col >= 124)) ax[rg][kk][j] = 0;
                        }
            }
        }

        // ---- head(t=e-2) for own 16 rows; wave w -> cols [16w,16w+16) ----
        if (doHD) {
            bf16x8 ahd[8];
            const char* ar = rs + (size_t)(obase + l15) * 1024 + 512 + l4 * 16;
            #pragma unroll
            for (int kk = 0; kk < 8; kk++) ahd[kk] = *(const bf16x8*)(ar + kk * 64);
            f32x4 hc; hc[0] = bbHD; hc[1] = bbHD; hc[2] = bbHD; hc[3] = bbHD;
            #pragma unroll
            for (int kk = 0; kk < 8; kk++)
                hc = __builtin_amdgcn_mfma_f32_16x16x32_bf16(ahd[kk], whd[kk], hc, 0, 0, 0);
            #pragma unroll
            for (int q = 0; q < 4; q++)
                headbuf[l4 * 4 + q][w * 16 + l15] = hc[q];
            __syncthreads();

            // ---- softmaxes + lp: half-wave per row ----
            const int sr = obase + srow;
            float4 v4 = *(const float4*)&headbuf[srow][4 * ln];
            const float NINF = -__builtin_inff();

            // token softmax over cols 0..19 (masked)
            float t0 = NINF, t1 = NINF, t2 = NINF, t3 = NINF;
            if (ln < 5) {
                const int4 mk = *(const int4*)(masks + ((size_t)sr * TS + tH) * VV + 4 * ln);
                t0 = mk.x ? v4.x : -1e9f;
                t1 = mk.y ? v4.y : -1e9f;
                t2 = mk.z ? v4.z : -1e9f;
                t3 = mk.w ? v4.w : -1e9f;
            }
            float m = fmaxf(fmaxf(t0, t1), fmaxf(t2, t3));
            #pragma unroll
            for (int off = 16; off; off >>= 1) m = fmaxf(m, __shfl_xor(m, off));
            float ee = (ln < 5) ? (__expf(t0 - m) + __expf(t1 - m) + __expf(t2 - m) + __expf(t3 - m)) : 0.f;
            #pragma unroll
            for (int off = 16; off; off >>= 1) ee += __shfl_xor(ee, off);
            float lse = m + __logf(ee);
            int ch = choices_lds[srow][tH];
            int cm = ch & 3;
            float chsel = (cm == 0) ? t0 : (cm == 1) ? t1 : (cm == 2) ? t2 : t3;
            float chlog = __shfl(chsel, (ch >> 2) + (half << 5));
            float lpadd = chlog - lse;

            // class softmax over cols 20..119
            const bool a2 = (ln >= 5) && (ln < 30);
            float u0 = a2 ? v4.x : NINF, u1 = a2 ? v4.y : NINF;
            float u2 = a2 ? v4.z : NINF, u3 = a2 ? v4.w : NINF;
            float mc = fmaxf(fmaxf(u0, u1), fmaxf(u2, u3));
            #pragma unroll
            for (int off = 16; off; off >>= 1) mc = fmaxf(mc, __shfl_xor(mc, off));
            float ec = a2 ? (__expf(u0 - mc) + __expf(u1 - mc) + __expf(u2 - mc) + __expf(u3 - mc)) : 0.f;
            #pragma unroll
            for (int off = 16; off; off >>= 1) ec += __shfl_xor(ec, off);
            float lsec = mc + __logf(ec);
            int ci = cidx_lds[srow][tH];
            if (ci) {
                int col2 = VV + cch_lds[srow][tH];
                int sm = col2 & 3;
                float cand = (sm == 0) ? u0 : (sm == 1) ? u1 : (sm == 2) ? u2 : u3;
                float clog = __shfl(cand, (col2 >> 2) + (half << 5));
                lpadd += clog - lsec;
            }
            lp += lpadd;
        }

        // ---- L0(t=e): K = [h0(e-1) | xbits(e) | 1] ----
        if (doL0) {
            f32x4 acc0[2][4];
            #pragma unroll
            for (int rg = 0; rg < 2; rg++)
                #pragma unroll
                for (int gt = 0; gt < 4; gt++) { f32x4 z; z[0]=z[1]=z[2]=z[3]=0.f; acc0[rg][gt] = z; }
            #pragma unroll
            for (int kk = 0; kk < 12; kk++) {
                bf16x8 b0 = *(const bf16x8*)&ldsL0[0][kk][lane];
                bf16x8 b1 = *(const bf16x8*)&ldsL0[1][kk][lane];
                bf16x8 b2 = *(const bf16x8*)&ldsL0[2][kk][lane];
                bf16x8 b3 = *(const bf16x8*)&ldsL0[3][kk][lane];
                bf16x8 va0 = (kk < 8) ? a0[0][kk] : ax[0][kk - 8];
                bf16x8 va1 = (kk < 8) ? a0[1][kk] : ax[1][kk - 8];
                acc0[0][0] = __builtin_amdgcn_mfma_f32_16x16x32_bf16(va0, b0, acc0[0][0], 0, 0, 0);
                acc0[1][0] = __builtin_amdgcn_mfma_f32_16x16x32_bf16(va1, b0, acc0[1][0], 0, 0, 0);
                acc0[0][1] = __builtin_amdgcn_mfma_f32_16x16x32_bf16(va0, b1, acc0[0][1], 0, 0, 0);
                acc0[1][1] = __builtin_amdgcn_mfma_f32_16x16x32_bf16(va1, b1, acc0[1][1], 0, 0, 0);
                acc0[0][2] = __builtin_amdgcn_mfma_f32_16x16x32_bf16(va0, b2, acc0[0][2], 0, 0, 0);
                acc0[1][2] = __builtin_amdgcn_mfma_f32_16x16x32_bf16(va1, b2, acc0[1][2], 0, 0, 0);
                acc0[0][3] = __builtin_amdgcn_mfma_f32_16x16x32_bf16(va0, b3, acc0[0][3], 0, 0, 0);
                acc0[1][3] = __builtin_amdgcn_mfma_f32_16x16x32_bf16(va1, b3, acc0[1][3], 0, 0, 0);
            }
            #pragma unroll
            for (int rg = 0; rg < 2; rg++)
                #pragma unroll
                for (int q = 0; q < 4; q++) {
                    float iv = sigmoidf_(acc0[rg][0][q]);
                    float fv = sigmoidf_(acc0[rg][1][q]);
                    float gv = tanhf_(acc0[rg][2][q]);
                    float ov = sigmoidf_(acc0[rg][3][q]);
                    float cn = fv * c0r[rg][q] + iv * gv;
                    c0r[rg][q] = cn;
                    *(unsigned short*)(wsl + (size_t)(crow0 + 16 * rg + q) * 1024
                                       + (16 * rank + l15) * 2) = f2bf(ov * tanhf_(cn));
                }
        }

        // ---- L1(t=e-1): K = [h0(e-1) | h1(e-2)] ----
        if (doL1) {
            f32x4 acc1[2][4];
            #pragma unroll
            for (int rg = 0; rg < 2; rg++)
                #pragma unroll
                for (int gt = 0; gt < 4; gt++) { f32x4 z; z[0]=z[1]=z[2]=z[3]=bb1[gt]; acc1[rg][gt] = z; }
            #pragma unroll
            for (int kk = 0; kk < 16; kk++) {
                bf16x8 b0 = *(const bf16x8*)&ldsL1[0][kk][lane];
                bf16x8 b1 = *(const bf16x8*)&ldsL1[1][kk][lane];
                bf16x8 b2 = *(const bf16x8*)&ldsL1[2][kk][lane];
                bf16x8 b3 = *(const bf16x8*)&ldsL1[3][kk][lane];
                bf16x8 va0 = (kk < 8) ? a0[0][kk] : a1[0][kk - 8];
                bf16x8 va1 = (kk < 8) ? a0[1][kk] : a1[1][kk - 8];
                acc1[0][0] = __builtin_amdgcn_mfma_f32_16x16x32_bf16(va0, b0, acc1[0][0], 0, 0, 0);
                acc1[1][0] = __builtin_amdgcn_mfma_f32_16x16x32_bf16(va1, b0, acc1[1][0], 0, 0, 0);
                acc1[0][1] = __builtin_amdgcn_mfma_f32_16x16x32_bf16(va0, b1, acc1[0][1], 0, 0, 0);
                acc1[1][1] = __builtin_amdgcn_mfma_f32_16x16x32_bf16(va1, b1, acc1[1][1], 0, 0, 0);
                acc1[0][2] = __builtin_amdgcn_mfma_f32_16x16x32_bf16(va0, b2, acc1[0][2], 0, 0, 0);
                acc1[1][2] = __builtin_amdgcn_mfma_f32_16x16x32_bf16(va1, b2, acc1[1][2], 0, 0, 0);
                acc1[0][3] = __builtin_amdgcn_mfma_f32_16x16x32_bf16(va0, b3, acc1[0][3], 0, 0, 0);
                acc1[1][3] = __builtin_amdgcn_mfma_f32_16x16x32_bf16(va1, b3, acc1[1][3], 0, 0, 0);
            }
            #pragma unroll
            for (int rg = 0; rg < 2; rg++)
                #pragma unroll
                for (int q = 0; q < 4; q++) {
                    float iv = sigmoidf_(acc1[rg][0][q]);
                    float fv = sigmoidf_(acc1[rg][1][q]);
                    float gv = tanhf_(acc1[rg][2][q]);
                    float ov = sigmoidf_(acc1[rg][3][q]);
                    float cn = fv * c1r[rg][q] + iv * gv;
                    c1r[rg][q] = cn;
                    *(unsigned short*)(wsl + (size_t)(crow0 + 16 * rg + q) * 1024 + 512
                                       + (16 * rank + l15) * 2) = f2bf(ov * tanhf_(cn));
                }
        }

        if (e <= 31) { gsync(cnt, tgt); tgt += NRANK; }
    }

    if (ln == 0) out[obase + srow] = lp;
}

extern "C" void kernel_launch(void* const* d_in, const int* in_sizes, int n_in,
                              void* d_out, int out_size, void* d_ws, size_t ws_size,
                              hipStream_t stream) {
    const float* x        = (const float*)d_in[0];
    const int*   choices  = (const int*)d_in[1];
    const int*   masks    = (const int*)d_in[2];
    const int*   c_idx    = (const int*)d_in[3];
    const int*   c_choice = (const int*)d_in[4];
    const float* Wih0 = (const float*)d_in[5];
    const float* Whh0 = (const float*)d_in[6];
    const float* bih0 = (const float*)d_in[7];
    const float* bhh0 = (const float*)d_in[8];
    const float* Wih1 = (const float*)d_in[9];
    const float* Whh1 = (const float*)d_in[10];
    const float* bih1 = (const float*)d_in[11];
    const float* bhh1 = (const float*)d_in[12];
    const float* Wout = (const float*)d_in[13];
    const float* bout = (const float*)d_in[14];
    const float* Wxc  = (const float*)d_in[15];
    const float* bxc  = (const float*)d_in[16];
    const float* Wcv  = (const float*)d_in[17];
    const float* bcv  = (const float*)d_in[18];
    char* ws = (char*)d_ws;

    hipMemsetAsync(ws + OFF_SYNC, 0, 1024, stream);
    hipMemsetAsync(ws + OFF_HBUF, 0, 2 * HSLOT, stream);

    hipLaunchKernelGGL(prep_kernel, dim3(469), dim3(256), 0, stream,
                       Wih0, Whh0, bih0, bhh0, Wih1, Whh1, bih1, bhh1,
                       Wout, bout, Wcv, bcv, ws);
    hipLaunchKernelGGL(lstm_main, dim3(256), dim3(512), 0, stream,
                       x, choices, masks, c_idx, c_choice,
                       Wxc, bxc, ws, (float*)d_out);
}

// Round 7
// 1004.145 us; speedup vs baseline: 2.9331x; 1.3542x over previous
//
#include <hip/hip_runtime.h>
#include <hip/hip_bf16.h>

// Problem sizes (fixed)
#define BSZ  4096
#define TS   31
#define DIN  124
#define HH   256
#define FEA  64
#define VV   20
#define NCC  100

#define NGROUP 16          // groups
#define NRANK  16          // blocks per group (hidden slices)
#define GROWS  256         // batch rows per group

typedef __attribute__((ext_vector_type(8))) short bf16x8;   // 8 bf16 = 4 VGPR
typedef __attribute__((ext_vector_type(4))) float f32x4;

// ---- workspace layout (bytes) ----
#define OFF_WL0   0u          // 64 tiles x 12 kk x 1KB = 786432
#define OFF_WL1   786432u     // 64 tiles x 16 kk x 1KB = 1048576
#define OFF_WHD   1835008u    // 8 tiles x 8 kk x 1KB   = 65536
#define OFF_BG1   1900544u    // 1024 f32
#define OFF_BHD   1904640u    // 128 f32
#define OFF_SYNC  1905664u    // 16 groups x 64B counters
#define OFF_HBUF  2956288u    // 2 x [4096][512] bf16 (h0 cols 0-255, h1 256-511)
#define HSLOT     4194304u    // one hbuf slot

__device__ __forceinline__ unsigned short f2bf(float f) {
    unsigned int u = __float_as_uint(f);
    unsigned int r = (u + 0x7FFFu + ((u >> 16) & 1u)) >> 16;
    return (unsigned short)r;
}
__device__ __forceinline__ float sigmoidf_(float x) {
    return 1.f / (1.f + __expf(-x));
}
__device__ __forceinline__ float tanhf_(float x) {
    float ax = fabsf(x);
    float e = __expf(-2.f * ax);
    float t = (1.f - e) / (1.f + e);
    return copysignf(t, x);
}

// ---- device-coherent exchange ops: COMPILER-TRACKED scoped atomics ----
// (agent scope => coherent cache bits; compiler manages liveness/waitcnts,
// so register spills are legal — unlike raw inline-asm loads)
union U16B { unsigned long long u[2]; bf16x8 v; };
__device__ __forceinline__ bf16x8 ld16cc(const void* p) {
    U16B x;
    x.u[0] = __hip_atomic_load((const unsigned long long*)p,
                               __ATOMIC_RELAXED, __HIP_MEMORY_SCOPE_AGENT);
    x.u[1] = __hip_atomic_load((const unsigned long long*)((const char*)p + 8),
                               __ATOMIC_RELAXED, __HIP_MEMORY_SCOPE_AGENT);
    return x.v;
}
__device__ __forceinline__ void st_agent_u16(void* p, unsigned short v) {
    __hip_atomic_store((unsigned short*)p, v, __ATOMIC_RELAXED, __HIP_MEMORY_SCOPE_AGENT);
}

// ---------------------------------------------------------------------------
// Prep: pack weights into MFMA B-fragment blocks (lane l of frag (tile,kk)
// holds W[16*tile + (l&15)][kk*32 + (l>>4)*8 + j], j=0..7). Fuse biases.
// ---------------------------------------------------------------------------
__global__ __launch_bounds__(256) void prep_kernel(
    const float* __restrict__ Wih0, const float* __restrict__ Whh0,
    const float* __restrict__ bih0, const float* __restrict__ bhh0,
    const float* __restrict__ Wih1, const float* __restrict__ Whh1,
    const float* __restrict__ bih1, const float* __restrict__ bhh1,
    const float* __restrict__ Wout, const float* __restrict__ bout,
    const float* __restrict__ Wcv,  const float* __restrict__ bcv,
    char* __restrict__ ws)
{
    const int NFRAG = 64*12 + 64*16 + 8*8;      // 1856
    int u = blockIdx.x * 256 + threadIdx.x;
    if (u < NFRAG * 64) {
        int fb = u >> 6;
        int l  = u & 63;
        int r15 = l & 15, l4 = l >> 4;
        unsigned short tmp[8];
        int4* dst;
        if (fb < 768) {                          // layer 0: [Whh0 | Wih0 | bias]
            int tile = fb / 12, kk = fb - tile * 12;
            int row = tile * 16 + r15;
            int k0  = kk * 32 + l4 * 8;
            #pragma unroll
            for (int j = 0; j < 8; j++) {
                int k = k0 + j;
                float v;
                if (k < 256) v = Whh0[row * HH + k];
                else {
                    int kp = k - 256;
                    v = (kp < DIN) ? Wih0[row * DIN + kp]
                      : (kp == DIN ? bih0[row] + bhh0[row] : 0.f);
                }
                tmp[j] = f2bf(v);
            }
            dst = (int4*)(ws + OFF_WL0) + fb * 64 + l;
        } else if (fb < 1792) {                  // layer 1: [Wih1 | Whh1]
            int f = fb - 768;
            int tile = f >> 4, kk = f & 15;
            int row = tile * 16 + r15;
            int k0  = kk * 32 + l4 * 8;
            #pragma unroll
            for (int j = 0; j < 8; j++) {
                int k = k0 + j;
                float v = (k < 256) ? Wih1[row * HH + k] : Whh1[row * HH + k - 256];
                tmp[j] = f2bf(v);
            }
            dst = (int4*)(ws + OFF_WL1) + f * 64 + l;
        } else {                                 // head: [Wout | Wcv | 0]
            int f = fb - 1792;
            int tile = f >> 3, kk = f & 7;
            int row = tile * 16 + r15;
            int k0  = kk * 32 + l4 * 8;
            #pragma unroll
            for (int j = 0; j < 8; j++) {
                int k = k0 + j;
                float v = (row < VV) ? Wout[row * HH + k]
                        : (row < VV + NCC ? Wcv[(row - VV) * HH + k] : 0.f);
                tmp[j] = f2bf(v);
            }
            dst = (int4*)(ws + OFF_WHD) + f * 64 + l;
        }
        *dst = *(const int4*)tmp;
    } else if (u < NFRAG * 64 + 1024) {
        int g = u - NFRAG * 64;
        ((float*)(ws + OFF_BG1))[g] = bih1[g] + bhh1[g];
    } else if (u < NFRAG * 64 + 1024 + 128) {
        int v = u - NFRAG * 64 - 1024;
        float b = (v < VV) ? bout[v] : (v < VV + NCC ? bcv[v - VV] : 0.f);
        ((float*)(ws + OFF_BHD))[v] = b;
    }
}

// ---------------------------------------------------------------------------
// group sync, fence-free: exchange data moves via agent-coherent atomics.
// arrive: drain own VMEM (syncthreads emits full drain; explicit belt+braces)
//         then thread0 relaxed agent add (data at coherence pt before flag).
// wait:   poll counter -> barrier -> sched fence.
// ---------------------------------------------------------------------------
__device__ __forceinline__ void g_arrive(unsigned* cnt) {
    asm volatile("s_waitcnt vmcnt(0)" ::: "memory");   // no outputs: safe asm
    __syncthreads();
    if (threadIdx.x == 0)
        __hip_atomic_fetch_add(cnt, 1u, __ATOMIC_RELAXED, __HIP_MEMORY_SCOPE_AGENT);
}
__device__ __forceinline__ void g_wait(unsigned* cnt, unsigned target) {
    if (threadIdx.x == 0) {
        while (__hip_atomic_load(cnt, __ATOMIC_RELAXED, __HIP_MEMORY_SCOPE_AGENT) < target)
            __builtin_amdgcn_s_sleep(2);
    }
    __syncthreads();
    __builtin_amdgcn_sched_barrier(0);
}

// ---------------------------------------------------------------------------
// Main: grid = 256 (1/CU). g = bid&15 (group; all 16 ranks share an XCD under
// %8 round-robin — perf-only assumption), rank = bid>>4 owns hidden slice
// [16*rank,16*rank+16), weights in LDS. 512 threads (8 waves); wave w handles
// group rows [32w,32w+32) for L0/L1, head col-tile w, softmax rows {2w,2w+1}.
// Epoch e: L0(t=e), L1(t=e-1), arrive, head+softmax(t=e-2) overlaps poll, wait.
// ---------------------------------------------------------------------------
__global__ __launch_bounds__(512, 2) void lstm_main(
    const float* __restrict__ x,        // [4096,64]
    const int*   __restrict__ choices,  // [4096,31]
    const int*   __restrict__ masks,    // [4096,31,20]
    const int*   __restrict__ c_idx,    // [4096,31]
    const int*   __restrict__ c_choice, // [4096,31]
    const float* __restrict__ Wxc,      // [256,64]
    const float* __restrict__ bxc,      // [256]
    char* __restrict__ ws,
    float* __restrict__ out)            // [4096]
{
    const int tid  = threadIdx.x;
    const int w    = tid >> 6;          // wave 0..7
    const int lane = tid & 63;
    const int l15  = lane & 15;
    const int l4   = lane >> 4;         // 0..3
    const int g    = blockIdx.x & 15;   // group
    const int rank = blockIdx.x >> 4;   // hidden slice

    __shared__ int4 ldsL0[4][12][64];   // 48KB
    __shared__ int4 ldsL1[4][16][64];   // 64KB
    __shared__ float headbuf[16][132];  // f32 logits for own 16 rows
    __shared__ int choices_lds[16][TS];
    __shared__ int cidx_lds[16][TS];
    __shared__ int cch_lds[16][TS];

    const int obase = g * GROWS + 16 * rank;      // own softmax rows base
    const int arow0 = g * GROWS + 32 * w + l15;   // A row (rg adds 16)
    const int crow0 = g * GROWS + 32 * w + l4*4;  // C row base (+16rg+q)

    // ---- load weight slices into LDS ----
    {
        const int4* src = (const int4*)(ws + OFF_WL0);
        for (int i = tid; i < 4 * 12 * 64; i += 512) {
            int gt = i / 768, r = i - gt * 768;
            ((int4*)ldsL0)[i] = src[((gt * 16 + rank) * 12) * 64 + r];
        }
        src = (const int4*)(ws + OFF_WL1);
        for (int i = tid; i < 4 * 16 * 64; i += 512) {
            int gt = i / 1024, r = i - gt * 1024;
            ((int4*)ldsL1)[i] = src[((gt * 16 + rank) * 16) * 64 + r];
        }
    }
    // head weight col-tile w in registers (persistent)
    bf16x8 whd[8];
    #pragma unroll
    for (int kk = 0; kk < 8; kk++)
        whd[kk] = *(const bf16x8*)(ws + OFF_WHD + ((size_t)(w * 8 + kk) * 64 + lane) * 16);

    // ---- bit-pack x-bits for this thread's two A-rows into registers ----
    // col c (0..123) = bit (c&31) of xb[rg][c>>5]; col 124 (bias) = bit 28 of xb[rg][3]
    unsigned xb[2][4];
    #pragma unroll
    for (int rg = 0; rg < 2; rg++) {
        xb[rg][0] = 0; xb[rg][1] = 0; xb[rg][2] = 0; xb[rg][3] = 0;
        const int rr = arow0 + 16 * rg;
        #pragma unroll
        for (int t = 0; t < TS; t++) {           // fully unrolled: static indices
            int ch = choices[rr * TS + t];
            #pragma unroll
            for (int i = 0; i < 4; i++) {
                const int col = 4 * t + i;
                if ((ch >> (3 - i)) & 1) xb[rg][col >> 5] |= (1u << (col & 31));
            }
        }
        xb[rg][3] |= (1u << 28);                 // col 124 = 1.0 (bias slot)
    }

    // ---- preload per-row scalars into LDS ----
    for (int i = tid; i < 16 * TS; i += 512) {
        int r = i / TS, tt = i - r * TS;
        choices_lds[r][tt] = choices[(obase + r) * TS + tt];
        cidx_lds[r][tt]    = c_idx[(obase + r) * TS + tt];
        cch_lds[r][tt]     = c_choice[(obase + r) * TS + tt];
    }

    // ---- c0 = x @ Wxc.T + bxc ----
    float c0r[2][4], c1r[2][4];
    {
        const int unit = 16 * rank + l15;
        float acc[2][4] = {{0.f,0.f,0.f,0.f},{0.f,0.f,0.f,0.f}};
        #pragma unroll 4
        for (int k4 = 0; k4 < 16; k4++) {
            float4 wv = *(const float4*)(Wxc + unit * FEA + k4 * 4);
            #pragma unroll
            for (int rg = 0; rg < 2; rg++)
                #pragma unroll
                for (int q = 0; q < 4; q++) {
                    int row = g * GROWS + 32 * w + 16 * rg + l4 * 4 + q;
                    float4 xv = *(const float4*)(x + row * FEA + k4 * 4);
                    acc[rg][q] += wv.x*xv.x + wv.y*xv.y + wv.z*xv.z + wv.w*xv.w;
                }
        }
        float bb = bxc[unit];
        #pragma unroll
        for (int rg = 0; rg < 2; rg++)
            #pragma unroll
            for (int q = 0; q < 4; q++) { c0r[rg][q] = acc[rg][q] + bb; c1r[rg][q] = acc[rg][q] + bb; }
    }

    // hoisted biases
    float bb1[4], bbHD;
    {
        const float* bg1 = (const float*)(ws + OFF_BG1);
        #pragma unroll
        for (int gt = 0; gt < 4; gt++) bb1[gt] = bg1[(gt * 16 + rank) * 16 + l15];
        bbHD = ((const float*)(ws + OFF_BHD))[w * 16 + l15];
    }

    unsigned* cnt = (unsigned*)(ws + OFF_SYNC) + g * 16;
    unsigned tgt = NRANK;
    float lp = 0.f;
    const int half = lane >> 5, ln = lane & 31;
    const int srow = 2 * w + half;                // own softmax row (0..15)

    __syncthreads();

    for (int e = 0; e <= 32; e++) {
        const char* rs  = ws + OFF_HBUF + (size_t)((unsigned)(e + 1) & 1u) * HSLOT;
        char*       wsl = ws + OFF_HBUF + (size_t)((unsigned)e & 1u) * HSLOT;
        const bool doL0 = (e < TS);
        const bool doL1 = (e >= 1 && e <= TS);
        const bool doHD = (e >= 2);
        const int  tH   = e - 2;

        // ---- h0(e-1) fragments (shared by L0 and L1) ----
        bf16x8 a0[2][8];
        if (doL0 || doL1) {
            #pragma unroll
            for (int rg = 0; rg < 2; rg++) {
                const char* ar = rs + (size_t)(arow0 + 16 * rg) * 1024 + l4 * 16;
                #pragma unroll
                for (int kk = 0; kk < 8; kk++) a0[rg][kk] = ld16cc(ar + kk * 64);
            }
        }

        // ---- L0(t=e): K = [h0(e-1) | xbits(<=e) | 1] ----
        if (doL0) {
            // expand masked x-bit fragments from registers (no memory)
            bf16x8 ax[2][4];
            #pragma unroll
            for (int rg = 0; rg < 2; rg++)
                #pragma unroll
                for (int kk = 0; kk < 4; kk++)
                    #pragma unroll
                    for (int j = 0; j < 8; j++) {
                        const int cj = l4 * 8 + j;          // col = kk*32 + cj
                        int col = kk * 32 + cj;
                        bool take = (col < 4 * e) || (col == 124);
                        bool bit  = (xb[rg][kk] >> (col & 31)) & 1u;
                        ax[rg][kk][j] = (take && bit) ? (short)0x3F80 : (short)0;
                    }

            f32x4 acc0[2][4];
            #pragma unroll
            for (int rg = 0; rg < 2; rg++)
                #pragma unroll
                for (int gt = 0; gt < 4; gt++) { f32x4 z; z[0]=z[1]=z[2]=z[3]=0.f; acc0[rg][gt] = z; }
            #pragma unroll
            for (int kk = 0; kk < 12; kk++) {
                bf16x8 b0 = *(const bf16x8*)&ldsL0[0][kk][lane];
                bf16x8 b1 = *(const bf16x8*)&ldsL0[1][kk][lane];
                bf16x8 b2 = *(const bf16x8*)&ldsL0[2][kk][lane];
                bf16x8 b3 = *(const bf16x8*)&ldsL0[3][kk][lane];
                bf16x8 va0 = (kk < 8) ? a0[0][kk] : ax[0][kk - 8];
                bf16x8 va1 = (kk < 8) ? a0[1][kk] : ax[1][kk - 8];
                acc0[0][0] = __builtin_amdgcn_mfma_f32_16x16x32_bf16(va0, b0, acc0[0][0], 0, 0, 0);
                acc0[1][0] = __builtin_amdgcn_mfma_f32_16x16x32_bf16(va1, b0, acc0[1][0], 0, 0, 0);
                acc0[0][1] = __builtin_amdgcn_mfma_f32_16x16x32_bf16(va0, b1, acc0[0][1], 0, 0, 0);
                acc0[1][1] = __builtin_amdgcn_mfma_f32_16x16x32_bf16(va1, b1, acc0[1][1], 0, 0, 0);
                acc0[0][2] = __builtin_amdgcn_mfma_f32_16x16x32_bf16(va0, b2, acc0[0][2], 0, 0, 0);
                acc0[1][2] = __builtin_amdgcn_mfma_f32_16x16x32_bf16(va1, b2, acc0[1][2], 0, 0, 0);
                acc0[0][3] = __builtin_amdgcn_mfma_f32_16x16x32_bf16(va0, b3, acc0[0][3], 0, 0, 0);
                acc0[1][3] = __builtin_amdgcn_mfma_f32_16x16x32_bf16(va1, b3, acc0[1][3], 0, 0, 0);
            }
            #pragma unroll
            for (int rg = 0; rg < 2; rg++)
                #pragma unroll
                for (int q = 0; q < 4; q++) {
                    float iv = sigmoidf_(acc0[rg][0][q]);
                    float fv = sigmoidf_(acc0[rg][1][q]);
                    float gv = tanhf_(acc0[rg][2][q]);
                    float ov = sigmoidf_(acc0[rg][3][q]);
                    float cn = fv * c0r[rg][q] + iv * gv;
                    c0r[rg][q] = cn;
                    st_agent_u16(wsl + (size_t)(crow0 + 16 * rg + q) * 1024
                                 + (16 * rank + l15) * 2, f2bf(ov * tanhf_(cn)));
                }
        }

        // ---- L1(t=e-1): K = [h0(e-1) | h1(e-2)] ----
        if (doL1) {
            bf16x8 a1[2][8];
            #pragma unroll
            for (int rg = 0; rg < 2; rg++) {
                const char* ar = rs + (size_t)(arow0 + 16 * rg) * 1024 + 512 + l4 * 16;
                #pragma unroll
                for (int kk = 0; kk < 8; kk++) a1[rg][kk] = ld16cc(ar + kk * 64);
            }
            f32x4 acc1[2][4];
            #pragma unroll
            for (int rg = 0; rg < 2; rg++)
                #pragma unroll
                for (int gt = 0; gt < 4; gt++) { f32x4 z; z[0]=z[1]=z[2]=z[3]=bb1[gt]; acc1[rg][gt] = z; }
            #pragma unroll
            for (int kk = 0; kk < 16; kk++) {
                bf16x8 b0 = *(const bf16x8*)&ldsL1[0][kk][lane];
                bf16x8 b1 = *(const bf16x8*)&ldsL1[1][kk][lane];
                bf16x8 b2 = *(const bf16x8*)&ldsL1[2][kk][lane];
                bf16x8 b3 = *(const bf16x8*)&ldsL1[3][kk][lane];
                bf16x8 va0 = (kk < 8) ? a0[0][kk] : a1[0][kk - 8];
                bf16x8 va1 = (kk < 8) ? a0[1][kk] : a1[1][kk - 8];
                acc1[0][0] = __builtin_amdgcn_mfma_f32_16x16x32_bf16(va0, b0, acc1[0][0], 0, 0, 0);
                acc1[1][0] = __builtin_amdgcn_mfma_f32_16x16x32_bf16(va1, b0, acc1[1][0], 0, 0, 0);
                acc1[0][1] = __builtin_amdgcn_mfma_f32_16x16x32_bf16(va0, b1, acc1[0][1], 0, 0, 0);
                acc1[1][1] = __builtin_amdgcn_mfma_f32_16x16x32_bf16(va1, b1, acc1[1][1], 0, 0, 0);
                acc1[0][2] = __builtin_amdgcn_mfma_f32_16x16x32_bf16(va0, b2, acc1[0][2], 0, 0, 0);
                acc1[1][2] = __builtin_amdgcn_mfma_f32_16x16x32_bf16(va1, b2, acc1[1][2], 0, 0, 0);
                acc1[0][3] = __builtin_amdgcn_mfma_f32_16x16x32_bf16(va0, b3, acc1[0][3], 0, 0, 0);
                acc1[1][3] = __builtin_amdgcn_mfma_f32_16x16x32_bf16(va1, b3, acc1[1][3], 0, 0, 0);
            }
            #pragma unroll
            for (int rg = 0; rg < 2; rg++)
                #pragma unroll
                for (int q = 0; q < 4; q++) {
                    float iv = sigmoidf_(acc1[rg][0][q]);
                    float fv = sigmoidf_(acc1[rg][1][q]);
                    float gv = tanhf_(acc1[rg][2][q]);
                    float ov = sigmoidf_(acc1[rg][3][q]);
                    float cn = fv * c1r[rg][q] + iv * gv;
                    c1r[rg][q] = cn;
                    st_agent_u16(wsl + (size_t)(crow0 + 16 * rg + q) * 1024 + 512
                                 + (16 * rank + l15) * 2, f2bf(ov * tanhf_(cn)));
                }
        }

        // ---- head A-fragments (own rows, h1(e-2)) then arrive early ----
        bf16x8 ahd[8];
        if (doHD) {
            const char* ar = rs + (size_t)(obase + l15) * 1024 + 512 + l4 * 16;
            #pragma unroll
            for (int kk = 0; kk < 8; kk++) ahd[kk] = ld16cc(ar + kk * 64);
        }
        if (e <= 31) g_arrive(cnt);

        // ---- head+softmax (t=e-2 data) overlaps other blocks' progress ----
        if (doHD) {
            f32x4 hc; hc[0] = bbHD; hc[1] = bbHD; hc[2] = bbHD; hc[3] = bbHD;
            #pragma unroll
            for (int kk = 0; kk < 8; kk++)
                hc = __builtin_amdgcn_mfma_f32_16x16x32_bf16(ahd[kk], whd[kk], hc, 0, 0, 0);
            #pragma unroll
            for (int q = 0; q < 4; q++)
                headbuf[l4 * 4 + q][w * 16 + l15] = hc[q];
            __syncthreads();

            const int sr = obase + srow;
            float4 v4 = *(const float4*)&headbuf[srow][4 * ln];
            const float NINF = -__builtin_inff();

            // token softmax over cols 0..19 (masked)
            float t0 = NINF, t1 = NINF, t2 = NINF, t3 = NINF;
            if (ln < 5) {
                const int4 mk = *(const int4*)(masks + ((size_t)sr * TS + tH) * VV + 4 * ln);
                t0 = mk.x ? v4.x : -1e9f;
                t1 = mk.y ? v4.y : -1e9f;
                t2 = mk.z ? v4.z : -1e9f;
                t3 = mk.w ? v4.w : -1e9f;
            }
            float m = fmaxf(fmaxf(t0, t1), fmaxf(t2, t3));
            #pragma unroll
            for (int off = 16; off; off >>= 1) m = fmaxf(m, __shfl_xor(m, off));
            float ee = (ln < 5) ? (__expf(t0 - m) + __expf(t1 - m) + __expf(t2 - m) + __expf(t3 - m)) : 0.f;
            #pragma unroll
            for (int off = 16; off; off >>= 1) ee += __shfl_xor(ee, off);
            float lse = m + __logf(ee);
            int ch = choices_lds[srow][tH];
            int cm = ch & 3;
            float chsel = (cm == 0) ? t0 : (cm == 1) ? t1 : (cm == 2) ? t2 : t3;
            float chlog = __shfl(chsel, (ch >> 2) + (half << 5));
            float lpadd = chlog - lse;

            // class softmax over cols 20..119
            const bool a2 = (ln >= 5) && (ln < 30);
            float u0 = a2 ? v4.x : NINF, u1 = a2 ? v4.y : NINF;
            float u2 = a2 ? v4.z : NINF, u3 = a2 ? v4.w : NINF;
            float mc = fmaxf(fmaxf(u0, u1), fmaxf(u2, u3));
            #pragma unroll
            for (int off = 16; off; off >>= 1) mc = fmaxf(mc, __shfl_xor(mc, off));
            float ec = a2 ? (__expf(u0 - mc) + __expf(u1 - mc) + __expf(u2 - mc) + __expf(u3 - mc)) : 0.f;
            #pragma unroll
            for (int off = 16; off; off >>= 1) ec += __shfl_xor(ec, off);
            float lsec = mc + __logf(ec);
            int ci = cidx_lds[srow][tH];
            if (ci) {
                int col2 = VV + cch_lds[srow][tH];
                int sm = col2 & 3;
                float cand = (sm == 0) ? u0 : (sm == 1) ? u1 : (sm == 2) ? u2 : u3;
                float clog = __shfl(cand, (col2 >> 2) + (half << 5));
                lpadd += clog - lsec;
            }
            lp += lpadd;
        }

        if (e <= 31) { g_wait(cnt, tgt); tgt += NRANK; }
    }

    if (ln == 0) out[obase + srow] = lp;
}

extern "C" void kernel_launch(void* const* d_in, const int* in_sizes, int n_in,
                              void* d_out, int out_size, void* d_ws, size_t ws_size,
                              hipStream_t stream) {
    const float* x        = (const float*)d_in[0];
    const int*   choices  = (const int*)d_in[1];
    const int*   masks    = (const int*)d_in[2];
    const int*   c_idx    = (const int*)d_in[3];
    const int*   c_choice = (const int*)d_in[4];
    const float* Wih0 = (const float*)d_in[5];
    const float* Whh0 = (const float*)d_in[6];
    const float* bih0 = (const float*)d_in[7];
    const float* bhh0 = (const float*)d_in[8];
    const float* Wih1 = (const float*)d_in[9];
    const float* Whh1 = (const float*)d_in[10];
    const float* bih1 = (const float*)d_in[11];
    const float* bhh1 = (const float*)d_in[12];
    const float* Wout = (const float*)d_in[13];
    const float* bout = (const float*)d_in[14];
    const float* Wxc  = (const float*)d_in[15];
    const float* bxc  = (const float*)d_in[16];
    const float* Wcv  = (const float*)d_in[17];
    const float* bcv  = (const float*)d_in[18];
    char* ws = (char*)d_ws;

    hipMemsetAsync(ws + OFF_SYNC, 0, 1024, stream);
    hipMemsetAsync(ws + OFF_HBUF, 0, 2 * HSLOT, stream);

    hipLaunchKernelGGL(prep_kernel, dim3(469), dim3(256), 0, stream,
                       Wih0, Whh0, bih0, bhh0, Wih1, Whh1, bih1, bhh1,
                       Wout, bout, Wcv, bcv, ws);
    hipLaunchKernelGGL(lstm_main, dim3(256), dim3(512), 0, stream,
                       x, choices, masks, c_idx, c_choice,
                       Wxc, bxc, ws, (float*)d_out);
}

// Round 8
// 673.460 us; speedup vs baseline: 4.3734x; 1.4910x over previous
//
#include <hip/hip_runtime.h>
#include <hip/hip_bf16.h>

// Problem sizes (fixed)
#define BSZ  4096
#define TS   31
#define DIN  124
#define HH   256
#define FEA  64
#define VV   20
#define NCC  100

#define NGROUP 16          // groups
#define NRANK  16          // blocks per group (hidden slices)
#define GROWS  256         // batch rows per group

typedef __attribute__((ext_vector_type(8))) short bf16x8;   // 8 bf16 = 4 VGPR
typedef __attribute__((ext_vector_type(4))) float f32x4;

// ---- workspace layout (bytes) ----
#define OFF_WL0   0u          // 64 tiles x 12 kk x 1KB = 786432
#define OFF_WL1   786432u     // 64 tiles x 16 kk x 1KB = 1048576
#define OFF_WHD   1835008u    // 8 tiles x 8 kk x 1KB   = 65536
#define OFF_BG1   1900544u    // 1024 f32
#define OFF_BHD   1904640u    // 128 f32
#define OFF_SYNC  1905664u    // 16 groups x 64B counters
#define OFF_HBUF  2956288u    // 2 slots x 16 groups x 2 layers x 128KB (frag-packed)
#define HSLOT     4194304u    // one hbuf slot (4MB)
#define GBYTES    262144u     // per-group bytes in a slot (2 layers x 128KB)
#define LBYTES    131072u     // per-layer bytes (16 rb x 8 kk x 1KB)

__device__ __forceinline__ unsigned short f2bf(float f) {
    unsigned int u = __float_as_uint(f);
    unsigned int r = (u + 0x7FFFu + ((u >> 16) & 1u)) >> 16;
    return (unsigned short)r;
}
__device__ __forceinline__ float sigmoidf_(float x) {
    return 1.f / (1.f + __expf(-x));
}
__device__ __forceinline__ float tanhf_(float x) {
    float ax = fabsf(x);
    float e = __expf(-2.f * ax);
    float t = (1.f - e) / (1.f + e);
    return copysignf(t, x);
}

// ---- device-coherent exchange ops: COMPILER-TRACKED scoped atomics ----
union U16B { unsigned long long u[2]; bf16x8 v; };
__device__ __forceinline__ bf16x8 ld16cc(const void* p) {
    U16B x;
    x.u[0] = __hip_atomic_load((const unsigned long long*)p,
                               __ATOMIC_RELAXED, __HIP_MEMORY_SCOPE_AGENT);
    x.u[1] = __hip_atomic_load((const unsigned long long*)((const char*)p + 8),
                               __ATOMIC_RELAXED, __HIP_MEMORY_SCOPE_AGENT);
    return x.v;
}
__device__ __forceinline__ void st_agent_u16(void* p, unsigned short v) {
    __hip_atomic_store((unsigned short*)p, v, __ATOMIC_RELAXED, __HIP_MEMORY_SCOPE_AGENT);
}

// ---------------------------------------------------------------------------
// Prep: pack weights into MFMA B-fragment blocks (lane l of frag (tile,kk)
// holds W[16*tile + (l&15)][kk*32 + (l>>4)*8 + j], j=0..7). Fuse biases.
// ---------------------------------------------------------------------------
__global__ __launch_bounds__(256) void prep_kernel(
    const float* __restrict__ Wih0, const float* __restrict__ Whh0,
    const float* __restrict__ bih0, const float* __restrict__ bhh0,
    const float* __restrict__ Wih1, const float* __restrict__ Whh1,
    const float* __restrict__ bih1, const float* __restrict__ bhh1,
    const float* __restrict__ Wout, const float* __restrict__ bout,
    const float* __restrict__ Wcv,  const float* __restrict__ bcv,
    char* __restrict__ ws)
{
    const int NFRAG = 64*12 + 64*16 + 8*8;      // 1856
    int u = blockIdx.x * 256 + threadIdx.x;
    if (u < NFRAG * 64) {
        int fb = u >> 6;
        int l  = u & 63;
        int r15 = l & 15, l4 = l >> 4;
        unsigned short tmp[8];
        int4* dst;
        if (fb < 768) {                          // layer 0: [Whh0 | Wih0 | bias]
            int tile = fb / 12, kk = fb - tile * 12;
            int row = tile * 16 + r15;
            int k0  = kk * 32 + l4 * 8;
            #pragma unroll
            for (int j = 0; j < 8; j++) {
                int k = k0 + j;
                float v;
                if (k < 256) v = Whh0[row * HH + k];
                else {
                    int kp = k - 256;
                    v = (kp < DIN) ? Wih0[row * DIN + kp]
                      : (kp == DIN ? bih0[row] + bhh0[row] : 0.f);
                }
                tmp[j] = f2bf(v);
            }
            dst = (int4*)(ws + OFF_WL0) + fb * 64 + l;
        } else if (fb < 1792) {                  // layer 1: [Wih1 | Whh1]
            int f = fb - 768;
            int tile = f >> 4, kk = f & 15;
            int row = tile * 16 + r15;
            int k0  = kk * 32 + l4 * 8;
            #pragma unroll
            for (int j = 0; j < 8; j++) {
                int k = k0 + j;
                float v = (k < 256) ? Wih1[row * HH + k] : Whh1[row * HH + k - 256];
                tmp[j] = f2bf(v);
            }
            dst = (int4*)(ws + OFF_WL1) + f * 64 + l;
        } else {                                 // head: [Wout | Wcv | 0]
            int f = fb - 1792;
            int tile = f >> 3, kk = f & 7;
            int row = tile * 16 + r15;
            int k0  = kk * 32 + l4 * 8;
            #pragma unroll
            for (int j = 0; j < 8; j++) {
                int k = k0 + j;
                float v = (row < VV) ? Wout[row * HH + k]
                        : (row < VV + NCC ? Wcv[(row - VV) * HH + k] : 0.f);
                tmp[j] = f2bf(v);
            }
            dst = (int4*)(ws + OFF_WHD) + f * 64 + l;
        }
        *dst = *(const int4*)tmp;
    } else if (u < NFRAG * 64 + 1024) {
        int g = u - NFRAG * 64;
        ((float*)(ws + OFF_BG1))[g] = bih1[g] + bhh1[g];
    } else if (u < NFRAG * 64 + 1024 + 128) {
        int v = u - NFRAG * 64 - 1024;
        float b = (v < VV) ? bout[v] : (v < VV + NCC ? bcv[v - VV] : 0.f);
        ((float*)(ws + OFF_BHD))[v] = b;
    }
}

// ---------------------------------------------------------------------------
// group sync, fence-free: exchange data moves via agent-coherent atomics.
// ---------------------------------------------------------------------------
__device__ __forceinline__ void g_arrive(unsigned* cnt) {
    asm volatile("s_waitcnt vmcnt(0)" ::: "memory");   // no outputs: safe asm
    __syncthreads();
    if (threadIdx.x == 0)
        __hip_atomic_fetch_add(cnt, 1u, __ATOMIC_RELAXED, __HIP_MEMORY_SCOPE_AGENT);
}
__device__ __forceinline__ void g_wait(unsigned* cnt, unsigned target) {
    if (threadIdx.x == 0) {
        while (__hip_atomic_load(cnt, __ATOMIC_RELAXED, __HIP_MEMORY_SCOPE_AGENT) < target)
            __builtin_amdgcn_s_sleep(2);
    }
    __syncthreads();
    __builtin_amdgcn_sched_barrier(0);
}

// ---------------------------------------------------------------------------
// Main: grid = 256 (1/CU). g = bid&15, rank = bid>>4 owns hidden slice
// [16*rank,16*rank+16), weights in LDS. 512 threads (8 waves); wave w handles
// group rows [32w,32w+32) for L0/L1, head col-tile w, softmax rows {2w,2w+1}.
// h-exchange buffer is MFMA-FRAG-PACKED per group: frag(rb,kk) = 1KB, lane l
// holds rows rb*16+(l&15), cols kk*32+(l>>4)*8..+8 — consumer reads are
// lane-contiguous 16B (fully coalesced).
// Epoch e: L0(t=e), L1(t=e-1), arrive, head+softmax(t=e-2) overlaps poll, wait.
// ---------------------------------------------------------------------------
__global__ __launch_bounds__(512, 2) void lstm_main(
    const float* __restrict__ x,        // [4096,64]
    const int*   __restrict__ choices,  // [4096,31]
    const int*   __restrict__ masks,    // [4096,31,20]
    const int*   __restrict__ c_idx,    // [4096,31]
    const int*   __restrict__ c_choice, // [4096,31]
    const float* __restrict__ Wxc,      // [256,64]
    const float* __restrict__ bxc,      // [256]
    char* __restrict__ ws,
    float* __restrict__ out)            // [4096]
{
    const int tid  = threadIdx.x;
    const int w    = tid >> 6;          // wave 0..7
    const int lane = tid & 63;
    const int l15  = lane & 15;
    const int l4   = lane >> 4;         // 0..3
    const int g    = blockIdx.x & 15;   // group
    const int rank = blockIdx.x >> 4;   // hidden slice

    __shared__ int4 ldsL0[4][12][64];   // 48KB
    __shared__ int4 ldsL1[4][16][64];   // 64KB
    __shared__ float headbuf[16][132];  // f32 logits for own 16 rows
    __shared__ int choices_lds[16][TS];
    __shared__ int cidx_lds[16][TS];
    __shared__ int cch_lds[16][TS];

    const int obase = g * GROWS + 16 * rank;      // own softmax rows base
    const int arow0 = g * GROWS + 32 * w + l15;   // global A row (for xb packing)

    // ---- load weight slices into LDS ----
    {
        const int4* src = (const int4*)(ws + OFF_WL0);
        for (int i = tid; i < 4 * 12 * 64; i += 512) {
            int gt = i / 768, r = i - gt * 768;
            ((int4*)ldsL0)[i] = src[((gt * 16 + rank) * 12) * 64 + r];
        }
        src = (const int4*)(ws + OFF_WL1);
        for (int i = tid; i < 4 * 16 * 64; i += 512) {
            int gt = i / 1024, r = i - gt * 1024;
            ((int4*)ldsL1)[i] = src[((gt * 16 + rank) * 16) * 64 + r];
        }
    }
    // head weight col-tile w in registers (persistent)
    bf16x8 whd[8];
    #pragma unroll
    for (int kk = 0; kk < 8; kk++)
        whd[kk] = *(const bf16x8*)(ws + OFF_WHD + ((size_t)(w * 8 + kk) * 64 + lane) * 16);

    // ---- bit-pack x-bits for this thread's two A-rows into registers ----
    unsigned xb[2][4];
    #pragma unroll
    for (int rg = 0; rg < 2; rg++) {
        xb[rg][0] = 0; xb[rg][1] = 0; xb[rg][2] = 0; xb[rg][3] = 0;
        const int rr = arow0 + 16 * rg;
        #pragma unroll
        for (int t = 0; t < TS; t++) {
            int ch = choices[rr * TS + t];
            #pragma unroll
            for (int i = 0; i < 4; i++) {
                const int col = 4 * t + i;
                if ((ch >> (3 - i)) & 1) xb[rg][col >> 5] |= (1u << (col & 31));
            }
        }
        xb[rg][3] |= (1u << 28);                 // col 124 = 1.0 (bias slot)
    }

    // ---- preload per-row scalars into LDS ----
    for (int i = tid; i < 16 * TS; i += 512) {
        int r = i / TS, tt = i - r * TS;
        choices_lds[r][tt] = choices[(obase + r) * TS + tt];
        cidx_lds[r][tt]    = c_idx[(obase + r) * TS + tt];
        cch_lds[r][tt]     = c_choice[(obase + r) * TS + tt];
    }

    // ---- c0 = x @ Wxc.T + bxc ----
    float c0r[2][4], c1r[2][4];
    {
        const int unit = 16 * rank + l15;
        float acc[2][4] = {{0.f,0.f,0.f,0.f},{0.f,0.f,0.f,0.f}};
        #pragma unroll 4
        for (int k4 = 0; k4 < 16; k4++) {
            float4 wv = *(const float4*)(Wxc + unit * FEA + k4 * 4);
            #pragma unroll
            for (int rg = 0; rg < 2; rg++)
                #pragma unroll
                for (int q = 0; q < 4; q++) {
                    int row = g * GROWS + 32 * w + 16 * rg + l4 * 4 + q;
                    float4 xv = *(const float4*)(x + row * FEA + k4 * 4);
                    acc[rg][q] += wv.x*xv.x + wv.y*xv.y + wv.z*xv.z + wv.w*xv.w;
                }
        }
        float bb = bxc[unit];
        #pragma unroll
        for (int rg = 0; rg < 2; rg++)
            #pragma unroll
            for (int q = 0; q < 4; q++) { c0r[rg][q] = acc[rg][q] + bb; c1r[rg][q] = acc[rg][q] + bb; }
    }

    // hoisted biases
    float bb1[4], bbHD;
    {
        const float* bg1 = (const float*)(ws + OFF_BG1);
        #pragma unroll
        for (int gt = 0; gt < 4; gt++) bb1[gt] = bg1[(gt * 16 + rank) * 16 + l15];
        bbHD = ((const float*)(ws + OFF_BHD))[w * 16 + l15];
    }

    // ---- frag-packed exchange address bases ----
    // consumer read base (rb = 2w+rg, kk adds 1024): gb + rg*8192 + rd_base
    const unsigned rd_base = (unsigned)(2 * w * 8) * 1024u + (unsigned)lane * 16u;
    // head read base (rb = rank): layer1 + rank*8KB + lane*16
    const unsigned hd_base = LBYTES + (unsigned)(rank * 8) * 1024u + (unsigned)lane * 16u;
    // producer store base: frag (2w+rg, rank>>1), lane_in = (l4*4+q) + 16*scon,
    // byte 2*(l15&7) -> addr = gb + L*LBYTES + st_base + rg*8192 + q*16
    const unsigned scon = (2u * (unsigned)rank + (unsigned)(l15 >> 3)) & 3u;
    const unsigned st_base = ((unsigned)(2 * w * 8) + (unsigned)(rank >> 1)) * 1024u
                           + scon * 256u + (unsigned)(l4 * 4) * 16u
                           + 2u * (unsigned)(l15 & 7);

    unsigned* cnt = (unsigned*)(ws + OFF_SYNC) + g * 16;
    unsigned tgt = NRANK;
    float lp = 0.f;
    const int half = lane >> 5, ln = lane & 31;
    const int srow = 2 * w + half;                // own softmax row (0..15)

    __syncthreads();

    for (int e = 0; e <= 32; e++) {
        const char* gb_prev = ws + OFF_HBUF + (size_t)((unsigned)(e + 1) & 1u) * HSLOT + (size_t)g * GBYTES;
        char*       gb_cur  = (char*)(ws + OFF_HBUF + (size_t)((unsigned)e & 1u) * HSLOT + (size_t)g * GBYTES);
        const bool doL0 = (e < TS);
        const bool doL1 = (e >= 1 && e <= TS);
        const bool doHD = (e >= 2);
        const int  tH   = e - 2;

        // ---- h0(e-1) fragments (shared by L0 and L1): coalesced 16B/lane ----
        bf16x8 a0[2][8];
        if (doL0 || doL1) {
            #pragma unroll
            for (int rg = 0; rg < 2; rg++) {
                const char* ar = gb_prev + rd_base + rg * 8192u;
                #pragma unroll
                for (int kk = 0; kk < 8; kk++) a0[rg][kk] = ld16cc(ar + kk * 1024u);
            }
        }

        // ---- L0(t=e): K = [h0(e-1) | xbits(<=e) | 1] ----
        if (doL0) {
            bf16x8 ax[2][4];
            #pragma unroll
            for (int rg = 0; rg < 2; rg++)
                #pragma unroll
                for (int kk = 0; kk < 4; kk++)
                    #pragma unroll
                    for (int j = 0; j < 8; j++) {
                        const int cj = l4 * 8 + j;
                        int col = kk * 32 + cj;
                        bool take = (col < 4 * e) || (col == 124);
                        bool bit  = (xb[rg][kk] >> (col & 31)) & 1u;
                        ax[rg][kk][j] = (take && bit) ? (short)0x3F80 : (short)0;
                    }

            f32x4 acc0[2][4];
            #pragma unroll
            for (int rg = 0; rg < 2; rg++)
                #pragma unroll
                for (int gt = 0; gt < 4; gt++) { f32x4 z; z[0]=z[1]=z[2]=z[3]=0.f; acc0[rg][gt] = z; }
            #pragma unroll
            for (int kk = 0; kk < 12; kk++) {
                bf16x8 b0 = *(const bf16x8*)&ldsL0[0][kk][lane];
                bf16x8 b1 = *(const bf16x8*)&ldsL0[1][kk][lane];
                bf16x8 b2 = *(const bf16x8*)&ldsL0[2][kk][lane];
                bf16x8 b3 = *(const bf16x8*)&ldsL0[3][kk][lane];
                bf16x8 va0 = (kk < 8) ? a0[0][kk] : ax[0][kk - 8];
                bf16x8 va1 = (kk < 8) ? a0[1][kk] : ax[1][kk - 8];
                acc0[0][0] = __builtin_amdgcn_mfma_f32_16x16x32_bf16(va0, b0, acc0[0][0], 0, 0, 0);
                acc0[1][0] = __builtin_amdgcn_mfma_f32_16x16x32_bf16(va1, b0, acc0[1][0], 0, 0, 0);
                acc0[0][1] = __builtin_amdgcn_mfma_f32_16x16x32_bf16(va0, b1, acc0[0][1], 0, 0, 0);
                acc0[1][1] = __builtin_amdgcn_mfma_f32_16x16x32_bf16(va1, b1, acc0[1][1], 0, 0, 0);
                acc0[0][2] = __builtin_amdgcn_mfma_f32_16x16x32_bf16(va0, b2, acc0[0][2], 0, 0, 0);
                acc0[1][2] = __builtin_amdgcn_mfma_f32_16x16x32_bf16(va1, b2, acc0[1][2], 0, 0, 0);
                acc0[0][3] = __builtin_amdgcn_mfma_f32_16x16x32_bf16(va0, b3, acc0[0][3], 0, 0, 0);
                acc0[1][3] = __builtin_amdgcn_mfma_f32_16x16x32_bf16(va1, b3, acc0[1][3], 0, 0, 0);
            }
            #pragma unroll
            for (int rg = 0; rg < 2; rg++)
                #pragma unroll
                for (int q = 0; q < 4; q++) {
                    float iv = sigmoidf_(acc0[rg][0][q]);
                    float fv = sigmoidf_(acc0[rg][1][q]);
                    float gv = tanhf_(acc0[rg][2][q]);
                    float ov = sigmoidf_(acc0[rg][3][q]);
                    float cn = fv * c0r[rg][q] + iv * gv;
                    c0r[rg][q] = cn;
                    st_agent_u16(gb_cur + st_base + rg * 8192u + q * 16u,
                                 f2bf(ov * tanhf_(cn)));
                }
        }

        // ---- L1(t=e-1): K = [h0(e-1) | h1(e-2)] ----
        if (doL1) {
            bf16x8 a1[2][8];
            #pragma unroll
            for (int rg = 0; rg < 2; rg++) {
                const char* ar = gb_prev + LBYTES + rd_base + rg * 8192u;
                #pragma unroll
                for (int kk = 0; kk < 8; kk++) a1[rg][kk] = ld16cc(ar + kk * 1024u);
            }
            f32x4 acc1[2][4];
            #pragma unroll
            for (int rg = 0; rg < 2; rg++)
                #pragma unroll
                for (int gt = 0; gt < 4; gt++) { f32x4 z; z[0]=z[1]=z[2]=z[3]=bb1[gt]; acc1[rg][gt] = z; }
            #pragma unroll
            for (int kk = 0; kk < 16; kk++) {
                bf16x8 b0 = *(const bf16x8*)&ldsL1[0][kk][lane];
                bf16x8 b1 = *(const bf16x8*)&ldsL1[1][kk][lane];
                bf16x8 b2 = *(const bf16x8*)&ldsL1[2][kk][lane];
                bf16x8 b3 = *(const bf16x8*)&ldsL1[3][kk][lane];
                bf16x8 va0 = (kk < 8) ? a0[0][kk] : a1[0][kk - 8];
                bf16x8 va1 = (kk < 8) ? a0[1][kk] : a1[1][kk - 8];
                acc1[0][0] = __builtin_amdgcn_mfma_f32_16x16x32_bf16(va0, b0, acc1[0][0], 0, 0, 0);
                acc1[1][0] = __builtin_amdgcn_mfma_f32_16x16x32_bf16(va1, b0, acc1[1][0], 0, 0, 0);
                acc1[0][1] = __builtin_amdgcn_mfma_f32_16x16x32_bf16(va0, b1, acc1[0][1], 0, 0, 0);
                acc1[1][1] = __builtin_amdgcn_mfma_f32_16x16x32_bf16(va1, b1, acc1[1][1], 0, 0, 0);
                acc1[0][2] = __builtin_amdgcn_mfma_f32_16x16x32_bf16(va0, b2, acc1[0][2], 0, 0, 0);
                acc1[1][2] = __builtin_amdgcn_mfma_f32_16x16x32_bf16(va1, b2, acc1[1][2], 0, 0, 0);
                acc1[0][3] = __builtin_amdgcn_mfma_f32_16x16x32_bf16(va0, b3, acc1[0][3], 0, 0, 0);
                acc1[1][3] = __builtin_amdgcn_mfma_f32_16x16x32_bf16(va1, b3, acc1[1][3], 0, 0, 0);
            }
            #pragma unroll
            for (int rg = 0; rg < 2; rg++)
                #pragma unroll
                for (int q = 0; q < 4; q++) {
                    float iv = sigmoidf_(acc1[rg][0][q]);
                    float fv = sigmoidf_(acc1[rg][1][q]);
                    float gv = tanhf_(acc1[rg][2][q]);
                    float ov = sigmoidf_(acc1[rg][3][q]);
                    float cn = fv * c1r[rg][q] + iv * gv;
                    c1r[rg][q] = cn;
                    st_agent_u16(gb_cur + LBYTES + st_base + rg * 8192u + q * 16u,
                                 f2bf(ov * tanhf_(cn)));
                }
        }

        // ---- head A-fragments (own rows rb=rank, h1(e-2)) then arrive early ----
        bf16x8 ahd[8];
        if (doHD) {
            const char* ar = gb_prev + hd_base;
            #pragma unroll
            for (int kk = 0; kk < 8; kk++) ahd[kk] = ld16cc(ar + kk * 1024u);
        }
        if (e <= 31) g_arrive(cnt);

        // ---- head+softmax (t=e-2 data) overlaps other blocks' progress ----
        if (doHD) {
            f32x4 hc; hc[0] = bbHD; hc[1] = bbHD; hc[2] = bbHD; hc[3] = bbHD;
            #pragma unroll
            for (int kk = 0; kk < 8; kk++)
                hc = __builtin_amdgcn_mfma_f32_16x16x32_bf16(ahd[kk], whd[kk], hc, 0, 0, 0);
            #pragma unroll
            for (int q = 0; q < 4; q++)
                headbuf[l4 * 4 + q][w * 16 + l15] = hc[q];
            __syncthreads();

            const int sr = obase + srow;
            float4 v4 = *(const float4*)&headbuf[srow][4 * ln];
            const float NINF = -__builtin_inff();

            // token softmax over cols 0..19 (masked)
            float t0 = NINF, t1 = NINF, t2 = NINF, t3 = NINF;
            if (ln < 5) {
                const int4 mk = *(const int4*)(masks + ((size_t)sr * TS + tH) * VV + 4 * ln);
                t0 = mk.x ? v4.x : -1e9f;
                t1 = mk.y ? v4.y : -1e9f;
                t2 = mk.z ? v4.z : -1e9f;
                t3 = mk.w ? v4.w : -1e9f;
            }
            float m = fmaxf(fmaxf(t0, t1), fmaxf(t2, t3));
            #pragma unroll
            for (int off = 16; off; off >>= 1) m = fmaxf(m, __shfl_xor(m, off));
            float ee = (ln < 5) ? (__expf(t0 - m) + __expf(t1 - m) + __expf(t2 - m) + __expf(t3 - m)) : 0.f;
            #pragma unroll
            for (int off = 16; off; off >>= 1) ee += __shfl_xor(ee, off);
            float lse = m + __logf(ee);
            int ch = choices_lds[srow][tH];
            int cm = ch & 3;
            float chsel = (cm == 0) ? t0 : (cm == 1) ? t1 : (cm == 2) ? t2 : t3;
            float chlog = __shfl(chsel, (ch >> 2) + (half << 5));
            float lpadd = chlog - lse;

            // class softmax over cols 20..119
            const bool a2 = (ln >= 5) && (ln < 30);
            float u0 = a2 ? v4.x : NINF, u1 = a2 ? v4.y : NINF;
            float u2 = a2 ? v4.z : NINF, u3 = a2 ? v4.w : NINF;
            float mc = fmaxf(fmaxf(u0, u1), fmaxf(u2, u3));
            #pragma unroll
            for (int off = 16; off; off >>= 1) mc = fmaxf(mc, __shfl_xor(mc, off));
            float ec = a2 ? (__expf(u0 - mc) + __expf(u1 - mc) + __expf(u2 - mc) + __expf(u3 - mc)) : 0.f;
            #pragma unroll
            for (int off = 16; off; off >>= 1) ec += __shfl_xor(ec, off);
            float lsec = mc + __logf(ec);
            int ci = cidx_lds[srow][tH];
            if (ci) {
                int col2 = VV + cch_lds[srow][tH];
                int sm = col2 & 3;
                float cand = (sm == 0) ? u0 : (sm == 1) ? u1 : (sm == 2) ? u2 : u3;
                float clog = __shfl(cand, (col2 >> 2) + (half << 5));
                lpadd += clog - lsec;
            }
            lp += lpadd;
        }

        if (e <= 31) { g_wait(cnt, tgt); tgt += NRANK; }
    }

    if (ln == 0) out[obase + srow] = lp;
}

extern "C" void kernel_launch(void* const* d_in, const int* in_sizes, int n_in,
                              void* d_out, int out_size, void* d_ws, size_t ws_size,
                              hipStream_t stream) {
    const float* x        = (const float*)d_in[0];
    const int*   choices  = (const int*)d_in[1];
    const int*   masks    = (const int*)d_in[2];
    const int*   c_idx    = (const int*)d_in[3];
    const int*   c_choice = (const int*)d_in[4];
    const float* Wih0 = (const float*)d_in[5];
    const float* Whh0 = (const float*)d_in[6];
    const float* bih0 = (const float*)d_in[7];
    const float* bhh0 = (const float*)d_in[8];
    const float* Wih1 = (const float*)d_in[9];
    const float* Whh1 = (const float*)d_in[10];
    const float* bih1 = (const float*)d_in[11];
    const float* bhh1 = (const float*)d_in[12];
    const float* Wout = (const float*)d_in[13];
    const float* bout = (const float*)d_in[14];
    const float* Wxc  = (const float*)d_in[15];
    const float* bxc  = (const float*)d_in[16];
    const float* Wcv  = (const float*)d_in[17];
    const float* bcv  = (const float*)d_in[18];
    char* ws = (char*)d_ws;

    hipMemsetAsync(ws + OFF_SYNC, 0, 1024, stream);
    hipMemsetAsync(ws + OFF_HBUF, 0, 2 * HSLOT, stream);

    hipLaunchKernelGGL(prep_kernel, dim3(469), dim3(256), 0, stream,
                       Wih0, Whh0, bih0, bhh0, Wih1, Whh1, bih1, bhh1,
                       Wout, bout, Wcv, bcv, ws);
    hipLaunchKernelGGL(lstm_main, dim3(256), dim3(512), 0, stream,
                       x, choices, masks, c_idx, c_choice,
                       Wxc, bxc, ws, (float*)d_out);
}